// Round 2
// baseline (651.368 us; speedup 1.0000x reference)
//
#include <hip/hip_runtime.h>
#include <hip/hip_bf16.h>

using bf16x8 = __attribute__((ext_vector_type(8))) __bf16;
using fx4    = __attribute__((ext_vector_type(4))) float;
using us4    = __attribute__((ext_vector_type(4))) unsigned short;
using us8    = __attribute__((ext_vector_type(8))) unsigned short;

__device__ __forceinline__ float b2f(unsigned short u) {
    unsigned int x = ((unsigned int)u) << 16;
    return __builtin_bit_cast(float, x);
}
__device__ __forceinline__ unsigned short f2b(float f) {
    __hip_bfloat16 h = __float2bfloat16(f);
    return __builtin_bit_cast(unsigned short, h);
}
__device__ __forceinline__ float logsigmoidf(float z) {
    return fminf(z, 0.0f) - log1pf(expf(-fabsf(z)));
}

// ---------------------------------------------------------------------------
// dtype detect: low 16 bits of each 32-bit word of x. bf16 data -> a real
// bf16 element (|v| <~ 6). fp32 data -> mantissa garbage (huge / NaN ~40%).
// flag = 1 -> inputs are fp32 ; flag = 0 -> inputs are bf16.
// ---------------------------------------------------------------------------
__global__ __launch_bounds__(256) void detect_kernel(
    const unsigned int* __restrict__ x, int* __restrict__ flag)
{
    __shared__ int bad[256];
    const int t = threadIdx.x;
    int b = 0;
#pragma unroll
    for (int i = 0; i < 16; ++i) {
        unsigned int w = x[t * 16 + i];
        float v = b2f((unsigned short)(w & 0xFFFFu));
        if (!(fabsf(v) < 1.0e6f)) b = 1;  // catches huge, Inf, NaN
    }
    bad[t] = b;
    __syncthreads();
    for (int s = 128; s > 0; s >>= 1) {
        if (t < s) bad[t] |= bad[t + s];
        __syncthreads();
    }
    if (t == 0) flag[0] = bad[0];
}

// canonicalize input -> packed bf16 (n elements, n % 4 == 0)
__global__ __launch_bounds__(256) void convert_kernel(
    const void* __restrict__ src, unsigned short* __restrict__ dst,
    int n, const int* __restrict__ flag)
{
    const int i = (blockIdx.x * 256 + threadIdx.x) * 4;
    if (i >= n) return;
    if (*flag) {
        const float* s = (const float*)src;
        fx4 v = *reinterpret_cast<const fx4*>(s + i);
        us4 r;
#pragma unroll
        for (int e = 0; e < 4; ++e) r[e] = f2b(v[e]);
        *reinterpret_cast<us4*>(dst + i) = r;
    } else {
        const unsigned short* s = (const unsigned short*)src;
        *reinterpret_cast<us4*>(dst + i) = *reinterpret_cast<const us4*>(s + i);
    }
}

// ---------------------------------------------------------------------------
// GEMM: C[M,N] = act( alpha * (A[M,K] @ W[N,K]^T) + bias )   (bf16 in)
// out: bf16, unless oflag!=nullptr and *oflag==1 -> fp32
// 128x128 block tile, 4 waves, each wave 64x64 via 4x4 mfma_f32_16x16x32_bf16
// ---------------------------------------------------------------------------
__global__ __launch_bounds__(256) void gemm_bt_kernel(
    const unsigned short* __restrict__ A, const unsigned short* __restrict__ W,
    unsigned short* __restrict__ C, int M, int N, int K,
    float alpha, const unsigned short* __restrict__ bias, int act,
    const int* __restrict__ oflag)
{
    __shared__ __align__(16) unsigned short As[128][72];  // +8 pad
    __shared__ __align__(16) unsigned short Bs[128][72];

    const int tid  = threadIdx.x;
    const int lane = tid & 63, wid = tid >> 6;
    const int quad = lane >> 4, l15 = lane & 15;
    const int wm = (wid & 1) * 64, wn = (wid >> 1) * 64;
    const int m0 = blockIdx.y * 128, n0 = blockIdx.x * 128;

    fx4 acc[4][4];
#pragma unroll
    for (int i = 0; i < 4; ++i)
#pragma unroll
        for (int j = 0; j < 4; ++j) acc[i][j] = fx4{0.f, 0.f, 0.f, 0.f};

    const int lrow = tid >> 3, lcol = (tid & 7) * 8;
    const unsigned short* Ab = A + (size_t)m0 * K;
    const unsigned short* Wb = W + (size_t)n0 * K;

    for (int k0 = 0; k0 < K; k0 += 64) {
#pragma unroll
        for (int p = 0; p < 4; ++p) {
            int r = lrow + p * 32;
            *reinterpret_cast<fx4*>(&As[r][lcol]) =
                *reinterpret_cast<const fx4*>(Ab + (size_t)r * K + k0 + lcol);
            *reinterpret_cast<fx4*>(&Bs[r][lcol]) =
                *reinterpret_cast<const fx4*>(Wb + (size_t)r * K + k0 + lcol);
        }
        __syncthreads();
#pragma unroll
        for (int ks = 0; ks < 2; ++ks) {
            const int koff = ks * 32 + quad * 8;
            bf16x8 af[4], bfr[4];
#pragma unroll
            for (int mt = 0; mt < 4; ++mt)
                af[mt] = *reinterpret_cast<const bf16x8*>(&As[wm + mt * 16 + l15][koff]);
#pragma unroll
            for (int nt = 0; nt < 4; ++nt)
                bfr[nt] = *reinterpret_cast<const bf16x8*>(&Bs[wn + nt * 16 + l15][koff]);
#pragma unroll
            for (int mt = 0; mt < 4; ++mt)
#pragma unroll
                for (int nt = 0; nt < 4; ++nt)
                    acc[mt][nt] = __builtin_amdgcn_mfma_f32_16x16x32_bf16(
                        af[mt], bfr[nt], acc[mt][nt], 0, 0, 0);
        }
        __syncthreads();
    }

    const int f32out = oflag ? *oflag : 0;  // uniform branch
    // epilogue: C row = (lane>>4)*4 + reg (A side), col = lane&15 (B side)
#pragma unroll
    for (int nt = 0; nt < 4; ++nt) {
        const int ncol = n0 + wn + nt * 16 + l15;
        const float bv = bias ? b2f(bias[ncol]) : 0.0f;
#pragma unroll
        for (int mt = 0; mt < 4; ++mt) {
#pragma unroll
            for (int r = 0; r < 4; ++r) {
                const int mrow = m0 + wm + mt * 16 + quad * 4 + r;
                float val = acc[mt][nt][r] * alpha + bv;
                if (act) val = val / (1.0f + __expf(-val));  // silu
                const size_t idx = (size_t)mrow * N + ncol;
                if (f32out) ((float*)C)[idx] = val;
                else        C[idx] = f2b(val);
            }
        }
    }
}

// ---------------------------------------------------------------------------
// kg16[m][n] = sum_k x[m][k] * Wkg1[n][k]   (M=4096, N=16, K=2048)
// ---------------------------------------------------------------------------
__global__ __launch_bounds__(256) void kg16_kernel(
    const unsigned short* __restrict__ x, const unsigned short* __restrict__ Wkg1,
    float* __restrict__ kg16)
{
    __shared__ __align__(16) float xs[2048];
    __shared__ float part[16][17];
    const int m = blockIdx.x;
    const int tid = threadIdx.x;
    us8 xv = *reinterpret_cast<const us8*>(x + (size_t)m * 2048 + tid * 8);
#pragma unroll
    for (int i = 0; i < 8; ++i) xs[tid * 8 + i] = b2f(xv[i]);
    __syncthreads();
    const int n = tid & 15, sl = tid >> 4;
    const unsigned short* wrow = Wkg1 + (size_t)n * 2048 + sl * 128;
    float s = 0.f;
#pragma unroll 8
    for (int i = 0; i < 128; ++i) s += xs[sl * 128 + i] * b2f(wrow[i]);
    part[sl][n] = s;
    __syncthreads();
    if (tid < 16) {
        float accv = 0.f;
#pragma unroll
        for (int g = 0; g < 16; ++g) accv += part[g][tid];
        kg16[m * 16 + tid] = accv;
    }
}

// ---------------------------------------------------------------------------
// Gate: kg = kg16 @ Wkg2^T + bkg2 ; g = logsigmoid(kg)/16 ;
// A[b][h][l][d] = inclusive cumsum_t(g) within chunk of 64
// ---------------------------------------------------------------------------
__global__ __launch_bounds__(256) void gate_kernel(
    const float* __restrict__ kg16, const unsigned short* __restrict__ Wkg2,
    const unsigned short* __restrict__ bkg2, float* __restrict__ Ag)
{
    __shared__ float kgs[64][17];
    const int blk = blockIdx.x;
    const int b = blk >> 5, ch = blk & 31;
    const int tid = threadIdx.x;
    {
        const int t = tid >> 2, j0 = (tid & 3) * 4;
        fx4 vv = *reinterpret_cast<const fx4*>(
            kg16 + ((size_t)(b * 2048 + ch * 64 + t)) * 16 + j0);
#pragma unroll
        for (int i = 0; i < 4; ++i) kgs[t][j0 + i] = vv[i];
    }
    const int c0 = tid * 4;
    float w[4][16], bb[4];
#pragma unroll
    for (int qi = 0; qi < 4; ++qi) {
#pragma unroll
        for (int j = 0; j < 16; ++j) w[qi][j] = b2f(Wkg2[(size_t)(c0 + qi) * 16 + j]);
        bb[qi] = b2f(bkg2[c0 + qi]);
    }
    __syncthreads();
    const int h = c0 >> 6, d0 = c0 & 63;
    float* outbase = Ag + ((size_t)(b * 16 + h) * 2048 + ch * 64) * 64 + d0;
    float accq[4] = {0.f, 0.f, 0.f, 0.f};
    for (int t = 0; t < 64; ++t) {
        fx4 st;
#pragma unroll
        for (int qi = 0; qi < 4; ++qi) {
            float z = bb[qi];
#pragma unroll
            for (int j = 0; j < 16; ++j) z += kgs[t][j] * w[qi][j];
            accq[qi] += logsigmoidf(z) * 0.0625f;
            st[qi] = accq[qi];
        }
        *reinterpret_cast<fx4*>(outbase + (size_t)t * 64) = st;
    }
}

// ---------------------------------------------------------------------------
// pass1: per chunk-head, T[d][j] = sum_s k[s][d]*exp(A63[d]-A[s][d]) * v[s][j]
// ---------------------------------------------------------------------------
__global__ __launch_bounds__(256) void pass1_kernel(
    const unsigned short* __restrict__ k, const unsigned short* __restrict__ v,
    const float* __restrict__ Ag, float* __restrict__ Tc)
{
    __shared__ __align__(16) float Als[64][68];
    __shared__ __align__(16) float kh[64][68];
    const int blk = blockIdx.x;
    const int ch = blk & 31, bh = blk >> 5;
    const int b = bh >> 4, h = bh & 15;
    const int tid = threadIdx.x;

    const float* Abase = Ag + ((size_t)bh * 2048 + ch * 64) * 64;
#pragma unroll
    for (int i = 0; i < 4; ++i) {
        int lf = tid + 256 * i;
        int t = lf >> 4, q4 = (lf & 15) * 4;
        *reinterpret_cast<fx4*>(&Als[t][q4]) =
            *reinterpret_cast<const fx4*>(Abase + (size_t)t * 64 + q4);
    }
    __syncthreads();
    const unsigned short* kbase = k + ((size_t)(b * 2048 + ch * 64)) * 1024 + h * 64;
#pragma unroll
    for (int i = 0; i < 16; ++i) {
        int lin = tid + 256 * i;
        int s = lin >> 6, d = lin & 63;
        kh[s][d] = b2f(kbase[(size_t)s * 1024 + d]) * __expf(Als[63][d] - Als[s][d]);
    }
    __syncthreads();
    const int d0 = (tid >> 4) * 4, j0 = (tid & 15) * 8;
    const unsigned short* vbase = v + ((size_t)(b * 2048 + ch * 64)) * 2048 + h * 128 + j0;
    float T[4][8];
#pragma unroll
    for (int a = 0; a < 4; ++a)
#pragma unroll
        for (int e = 0; e < 8; ++e) T[a][e] = 0.f;
    for (int s = 0; s < 64; ++s) {
        fx4 kv = *reinterpret_cast<const fx4*>(&kh[s][d0]);
        us8 vv = *reinterpret_cast<const us8*>(vbase + (size_t)s * 2048);
        float vf[8];
#pragma unroll
        for (int e = 0; e < 8; ++e) vf[e] = b2f(vv[e]);
#pragma unroll
        for (int a = 0; a < 4; ++a)
#pragma unroll
            for (int e = 0; e < 8; ++e) T[a][e] += kv[a] * vf[e];
    }
    float* tb = Tc + (size_t)blk * 8192 + d0 * 128 + j0;
#pragma unroll
    for (int a = 0; a < 4; ++a) {
        fx4 w1, w2;
#pragma unroll
        for (int e = 0; e < 4; ++e) { w1[e] = T[a][e]; w2[e] = T[a][4 + e]; }
        *reinterpret_cast<fx4*>(tb + a * 128) = w1;
        *reinterpret_cast<fx4*>(tb + a * 128 + 4) = w2;
    }
}

// ---------------------------------------------------------------------------
// combine: sequential scan over 32 chunks per (bh, j-slice). In-place.
// ---------------------------------------------------------------------------
__global__ __launch_bounds__(256) void combine_kernel(
    float* __restrict__ TS, const float* __restrict__ Ag)
{
    const int blk = blockIdx.x;
    const int js = blk & 3, bh = blk >> 2;
    const int tid = threadIdx.x;
    const int d = tid >> 2, joff = js * 32 + (tid & 3) * 8;
    float S[8] = {0.f, 0.f, 0.f, 0.f, 0.f, 0.f, 0.f, 0.f};
    const float* Abase = Ag + (size_t)bh * 2048 * 64;
    for (int c = 0; c < 32; ++c) {
        float* p = TS + ((size_t)(bh * 32 + c)) * 8192 + d * 128 + joff;
        fx4 t1 = *reinterpret_cast<const fx4*>(p);
        fx4 t2 = *reinterpret_cast<const fx4*>(p + 4);
        fx4 s1, s2;
#pragma unroll
        for (int e = 0; e < 4; ++e) { s1[e] = S[e]; s2[e] = S[4 + e]; }
        *reinterpret_cast<fx4*>(p) = s1;
        *reinterpret_cast<fx4*>(p + 4) = s2;
        const float dec = __expf(Abase[((size_t)c * 64 + 63) * 64 + d]);
#pragma unroll
        for (int e = 0; e < 4; ++e) {
            S[e]     = S[e]     * dec + t1[e];
            S[4 + e] = S[4 + e] * dec + t2[e];
        }
    }
}

// ---------------------------------------------------------------------------
// pass2: O = (q*e^A)@S_start + causal((q*e^A)(k*e^-A)^T)@V, then LayerNorm
// over dv=128, multiply by silu-gate, store y (bf16).
// ---------------------------------------------------------------------------
__global__ __launch_bounds__(256) void pass2_kernel(
    const unsigned short* __restrict__ q, const unsigned short* __restrict__ k,
    const unsigned short* __restrict__ v, const float* __restrict__ Ag,
    const float* __restrict__ Sst, const unsigned short* __restrict__ sg,
    unsigned short* __restrict__ y)
{
    __shared__ __align__(16) float qT[64][68];            // q~ transposed [d][t]
    __shared__ __align__(16) unsigned short kh2[64][64];  // k~ [s][d]
    __shared__ __align__(16) float PT[64][64];            // P^T [s][t]; LN reuse
    __shared__ __align__(16) unsigned short vs[64][128];  // v [s][j]

    const int blk = blockIdx.x;
    const int ch = blk & 31, bh = blk >> 5;
    const int b = bh >> 4, h = bh & 15;
    const int tid = threadIdx.x;
    const int t = tid & 63, wg = tid >> 6;

    const float* Abase = Ag + ((size_t)bh * 2048 + ch * 64) * 64;
    const unsigned short* qbase = q + ((size_t)(b * 2048 + ch * 64)) * 1024 + h * 64;
    const unsigned short* kbase = k + ((size_t)(b * 2048 + ch * 64)) * 1024 + h * 64;
    const unsigned short* vbase = v + ((size_t)(b * 2048 + ch * 64)) * 2048 + h * 128;

#pragma unroll
    for (int i = 0; i < 4; ++i) {
        int lf = tid + 256 * i;
        int s = lf >> 4, j8 = (lf & 15) * 8;
        *reinterpret_cast<us8*>(&vs[s][j8]) =
            *reinterpret_cast<const us8*>(vbase + (size_t)s * 2048 + j8);
    }
#pragma unroll
    for (int i = 0; i < 16; ++i) {
        int lin = tid + 256 * i;
        int s = lin >> 6, d = lin & 63;
        float a = Abase[(size_t)s * 64 + d];
        qT[d][s]  = b2f(qbase[(size_t)s * 1024 + d]) * __expf(a);
        kh2[s][d] = f2b(b2f(kbase[(size_t)s * 1024 + d]) * __expf(-a));
    }
    __syncthreads();
    {
        const int sb = wg * 16;
        float p[16];
#pragma unroll
        for (int si = 0; si < 16; ++si) p[si] = 0.f;
        for (int d = 0; d < 64; ++d) {
            float qv = qT[d][t];
#pragma unroll
            for (int si = 0; si < 16; ++si) p[si] += qv * b2f(kh2[sb + si][d]);
        }
#pragma unroll
        for (int si = 0; si < 16; ++si) PT[sb + si][t] = p[si];
    }
    __syncthreads();
    const int j0 = wg * 32;
    const float* Sg = Sst + (size_t)blk * 8192 + j0;
    float O[32];
#pragma unroll
    for (int jj = 0; jj < 32; ++jj) O[jj] = 0.f;
    for (int d = 0; d < 64; ++d) {
        float qv = qT[d][t];
#pragma unroll
        for (int g = 0; g < 8; ++g) {
            fx4 sv = *reinterpret_cast<const fx4*>(Sg + (size_t)d * 128 + g * 4);
            O[g * 4 + 0] += qv * sv[0];
            O[g * 4 + 1] += qv * sv[1];
            O[g * 4 + 2] += qv * sv[2];
            O[g * 4 + 3] += qv * sv[3];
        }
    }
    for (int s = 0; s < 64; ++s) {
        float pv = (s <= t) ? PT[s][t] : 0.0f;
#pragma unroll
        for (int g = 0; g < 4; ++g) {
            us8 vv = *reinterpret_cast<const us8*>(&vs[s][j0 + g * 8]);
#pragma unroll
            for (int e = 0; e < 8; ++e) O[g * 8 + e] += pv * b2f(vv[e]);
        }
    }
    __syncthreads();  // PT reads done; reuse as LN reduction buffer
    float s1 = 0.f, s2 = 0.f;
#pragma unroll
    for (int jj = 0; jj < 32; ++jj) { s1 += O[jj]; s2 += O[jj] * O[jj]; }
    float* red = &PT[0][0];
    red[wg * 64 + t] = s1;
    red[256 + wg * 64 + t] = s2;
    __syncthreads();
    const float S1 = red[t] + red[64 + t] + red[128 + t] + red[192 + t];
    const float S2 = red[256 + t] + red[320 + t] + red[384 + t] + red[448 + t];
    const float mu = S1 * (1.0f / 128.0f);
    const float var = S2 * (1.0f / 128.0f) - mu * mu;
    const float inv = rsqrtf(var + 1e-5f);
    const size_t obase = ((size_t)(b * 2048 + ch * 64 + t)) * 2048 + h * 128 + j0;
#pragma unroll
    for (int g = 0; g < 4; ++g) {
        us8 gv = *reinterpret_cast<const us8*>(sg + obase + g * 8);
        us8 ov;
#pragma unroll
        for (int e = 0; e < 8; ++e) {
            float on = (O[g * 8 + e] - mu) * inv;
            ov[e] = f2b(b2f(gv[e]) * on);
        }
        *reinterpret_cast<us8*>(y + obase + g * 8) = ov;
    }
}

// ---------------------------------------------------------------------------
extern "C" void kernel_launch(void* const* d_in, const int* in_sizes, int n_in,
                              void* d_out, int out_size, void* d_ws, size_t ws_size,
                              hipStream_t stream)
{
    unsigned short* out = (unsigned short*)d_out;

    char* ws = (char*)d_ws;
    size_t off = 0;
    auto alloc = [&](size_t bytes) -> void* {
        void* p = ws + off;
        off += (bytes + 255) & ~(size_t)255;
        return p;
    };
    // canonical bf16 copies of the 10 inputs
    unsigned short* xb    = (unsigned short*)alloc((size_t)4096 * 2048 * 2);
    unsigned short* Wqb   = (unsigned short*)alloc((size_t)1024 * 2048 * 2);
    unsigned short* Wkb   = (unsigned short*)alloc((size_t)1024 * 2048 * 2);
    unsigned short* Wkg1b = (unsigned short*)alloc((size_t)16 * 2048 * 2);
    unsigned short* Wkg2b = (unsigned short*)alloc((size_t)1024 * 16 * 2);
    unsigned short* bkg2b = (unsigned short*)alloc((size_t)1024 * 2);
    unsigned short* Wvb   = (unsigned short*)alloc((size_t)2048 * 2048 * 2);
    unsigned short* Wgb   = (unsigned short*)alloc((size_t)2048 * 2048 * 2);
    unsigned short* bgb   = (unsigned short*)alloc((size_t)2048 * 2);
    unsigned short* Wob   = (unsigned short*)alloc((size_t)2048 * 2048 * 2);
    // intermediates
    unsigned short* qb   = (unsigned short*)alloc((size_t)4096 * 1024 * 2);
    unsigned short* kb   = (unsigned short*)alloc((size_t)4096 * 1024 * 2);
    unsigned short* vb   = (unsigned short*)alloc((size_t)4096 * 2048 * 2);
    unsigned short* sgb  = (unsigned short*)alloc((size_t)4096 * 2048 * 2);
    unsigned short* yb   = (unsigned short*)alloc((size_t)4096 * 2048 * 2);
    float*          kg16 = (float*)alloc((size_t)4096 * 16 * 4);
    float*          Agb  = (float*)alloc((size_t)4096 * 1024 * 4);
    float*          TS   = (float*)alloc((size_t)1024 * 8192 * 4);
    int*            flag = (int*)alloc(256);

    detect_kernel<<<1, 256, 0, stream>>>((const unsigned int*)d_in[0], flag);

    struct { const void* src; unsigned short* dst; int n; } cv[10] = {
        { d_in[0], xb,    4096 * 2048 },
        { d_in[1], Wqb,   1024 * 2048 },
        { d_in[2], Wkb,   1024 * 2048 },
        { d_in[3], Wkg1b, 16 * 2048 },
        { d_in[4], Wkg2b, 1024 * 16 },
        { d_in[5], bkg2b, 1024 },
        { d_in[6], Wvb,   2048 * 2048 },
        { d_in[7], Wgb,   2048 * 2048 },
        { d_in[8], bgb,   2048 },
        { d_in[9], Wob,   2048 * 2048 },
    };
    for (int i = 0; i < 10; ++i) {
        int nthr = cv[i].n / 4;
        convert_kernel<<<(nthr + 255) / 256, 256, 0, stream>>>(
            cv[i].src, cv[i].dst, cv[i].n, flag);
    }

    const float SCALE = 0.08838834764831845f;  // 128**-0.5

    gemm_bt_kernel<<<dim3(8, 32),  256, 0, stream>>>(xb, Wqb, qb,  4096, 1024, 2048, 1.0f,  nullptr, 0, nullptr);
    gemm_bt_kernel<<<dim3(8, 32),  256, 0, stream>>>(xb, Wkb, kb,  4096, 1024, 2048, SCALE, nullptr, 0, nullptr);
    gemm_bt_kernel<<<dim3(16, 32), 256, 0, stream>>>(xb, Wvb, vb,  4096, 2048, 2048, 1.0f,  nullptr, 0, nullptr);
    gemm_bt_kernel<<<dim3(16, 32), 256, 0, stream>>>(xb, Wgb, sgb, 4096, 2048, 2048, 1.0f,  bgb,     1, nullptr);
    kg16_kernel<<<4096, 256, 0, stream>>>(xb, Wkg1b, kg16);
    gate_kernel<<<64, 256, 0, stream>>>(kg16, Wkg2b, bkg2b, Agb);
    pass1_kernel<<<1024, 256, 0, stream>>>(kb, vb, Agb, TS);
    combine_kernel<<<128, 256, 0, stream>>>(TS, Agb);
    pass2_kernel<<<1024, 256, 0, stream>>>(qb, kb, vb, Agb, TS, sgb, yb);
    gemm_bt_kernel<<<dim3(16, 32), 256, 0, stream>>>(yb, Wob, out, 4096, 2048, 2048, 1.0f, nullptr, 0, flag);
}

// Round 3
// 562.910 us; speedup vs baseline: 1.1571x; 1.1571x over previous
//
#include <hip/hip_runtime.h>
#include <hip/hip_bf16.h>

using bf16x8 = __attribute__((ext_vector_type(8))) __bf16;
using fx4    = __attribute__((ext_vector_type(4))) float;
using us4    = __attribute__((ext_vector_type(4))) unsigned short;
using us8    = __attribute__((ext_vector_type(8))) unsigned short;

__device__ __forceinline__ float b2f(unsigned short u) {
    unsigned int x = ((unsigned int)u) << 16;
    return __builtin_bit_cast(float, x);
}
__device__ __forceinline__ unsigned short f2b(float f) {
    __hip_bfloat16 h = __float2bfloat16(f);
    return __builtin_bit_cast(unsigned short, h);
}
__device__ __forceinline__ float logsigmoidf(float z) {
    return fminf(z, 0.0f) - log1pf(expf(-fabsf(z)));
}

// async 16B/lane global->LDS (dest = wave-uniform base + lane*16)
__device__ __forceinline__ void gl_lds16(const unsigned short* g, unsigned short* l) {
    __builtin_amdgcn_global_load_lds(
        (const __attribute__((address_space(1))) void*)g,
        (__attribute__((address_space(3))) void*)l, 16, 0, 0);
}

// 64-col bf16 LDS tile, 8-elem chunks XOR-swizzled by row&7 (2-way alias = free)
__device__ __forceinline__ bf16x8 frag64(const unsigned short* base, int row, int cq) {
    return *reinterpret_cast<const bf16x8*>(base + row * 64 + (((cq ^ (row & 7)) << 3)));
}
__device__ __forceinline__ int sw_idx(int row, int col) {
    return row * 64 + ((((col >> 3) ^ (row & 7)) << 3)) + (col & 7);
}

// ---------------------------------------------------------------------------
// dtype detect (flag=1 -> fp32 inputs) — unchanged from round 2 (passed)
// ---------------------------------------------------------------------------
__global__ __launch_bounds__(256) void detect_kernel(
    const unsigned int* __restrict__ x, int* __restrict__ flag)
{
    __shared__ int bad[256];
    const int t = threadIdx.x;
    int b = 0;
#pragma unroll
    for (int i = 0; i < 16; ++i) {
        unsigned int w = x[t * 16 + i];
        float v = b2f((unsigned short)(w & 0xFFFFu));
        if (!(fabsf(v) < 1.0e6f)) b = 1;
    }
    bad[t] = b;
    __syncthreads();
    for (int s = 128; s > 0; s >>= 1) {
        if (t < s) bad[t] |= bad[t + s];
        __syncthreads();
    }
    if (t == 0) flag[0] = bad[0];
}

__global__ __launch_bounds__(256) void convert_kernel(
    const void* __restrict__ src, unsigned short* __restrict__ dst,
    int n, const int* __restrict__ flag)
{
    const int i = (blockIdx.x * 256 + threadIdx.x) * 4;
    if (i >= n) return;
    if (*flag) {
        const float* s = (const float*)src;
        fx4 v = *reinterpret_cast<const fx4*>(s + i);
        us4 r;
#pragma unroll
        for (int e = 0; e < 4; ++e) r[e] = f2b(v[e]);
        *reinterpret_cast<us4*>(dst + i) = r;
    } else {
        const unsigned short* s = (const unsigned short*)src;
        *reinterpret_cast<us4*>(dst + i) = *reinterpret_cast<const us4*>(s + i);
    }
}

// ---------------------------------------------------------------------------
// GEMM v2 (m97 structure): BK=64, XOR-swizzled unpadded LDS, global_load_lds.
// C[M,N] = act(alpha*(A@W^T)+bias); bf16 in; out bf16 or fp32 via *oflag.
// ---------------------------------------------------------------------------
__global__ __launch_bounds__(256) void gemm_bt_kernel(
    const unsigned short* __restrict__ A, const unsigned short* __restrict__ W,
    unsigned short* __restrict__ C, int M, int N, int K,
    float alpha, const unsigned short* __restrict__ bias, int act,
    const int* __restrict__ oflag)
{
    __shared__ __align__(16) unsigned short As[128 * 64];
    __shared__ __align__(16) unsigned short Bs[128 * 64];

    const int tid  = threadIdx.x;
    const int lane = tid & 63, wid = tid >> 6;
    const int quad = lane >> 4, l15 = lane & 15;
    const int wm = (wid & 1) * 64, wn = (wid >> 1) * 64;
    const int m0 = blockIdx.y * 128, n0 = blockIdx.x * 128;

    fx4 acc[4][4];
#pragma unroll
    for (int i = 0; i < 4; ++i)
#pragma unroll
        for (int j = 0; j < 4; ++j) acc[i][j] = fx4{0.f, 0.f, 0.f, 0.f};

    const int srow = lane >> 3;                 // 0..7 row within a wave-load
    const int g8   = ((lane & 7) ^ srow) * 8;   // swizzled source k-chunk
    const int c8   = (lane & 7) * 8;            // stored chunk offset
    const unsigned short* Ab = A + (size_t)m0 * K;
    const unsigned short* Wb = W + (size_t)n0 * K;

    for (int k0 = 0; k0 < K; k0 += 64) {
#pragma unroll
        for (int p = 0; p < 4; ++p) {
            const int la  = wid * 4 + p;        // 16 loads cover 128 rows
            const int row = la * 8 + srow;
            gl_lds16(Ab + (size_t)row * K + k0 + g8, As + row * 64 + c8);
            gl_lds16(Wb + (size_t)row * K + k0 + g8, Bs + row * 64 + c8);
        }
        __syncthreads();
#pragma unroll
        for (int ks = 0; ks < 2; ++ks) {
            const int cq = quad + ks * 4;
            bf16x8 af[4], bfr[4];
#pragma unroll
            for (int mt = 0; mt < 4; ++mt) af[mt] = frag64(As, wm + mt * 16 + l15, cq);
#pragma unroll
            for (int nt = 0; nt < 4; ++nt) bfr[nt] = frag64(Bs, wn + nt * 16 + l15, cq);
#pragma unroll
            for (int mt = 0; mt < 4; ++mt)
#pragma unroll
                for (int nt = 0; nt < 4; ++nt)
                    acc[mt][nt] = __builtin_amdgcn_mfma_f32_16x16x32_bf16(
                        af[mt], bfr[nt], acc[mt][nt], 0, 0, 0);
        }
        __syncthreads();
    }

    const int f32out = oflag ? *oflag : 0;
#pragma unroll
    for (int nt = 0; nt < 4; ++nt) {
        const int ncol = n0 + wn + nt * 16 + l15;
        const float bv = bias ? b2f(bias[ncol]) : 0.0f;
#pragma unroll
        for (int mt = 0; mt < 4; ++mt) {
#pragma unroll
            for (int r = 0; r < 4; ++r) {
                const int mrow = m0 + wm + mt * 16 + quad * 4 + r;
                float val = acc[mt][nt][r] * alpha + bv;
                if (act) val = val / (1.0f + __expf(-val));
                const size_t idx = (size_t)mrow * N + ncol;
                if (f32out) ((float*)C)[idx] = val;
                else        C[idx] = f2b(val);
            }
        }
    }
}

// ---------------------------------------------------------------------------
// kg16 / gate — unchanged (passed, tiny)
// ---------------------------------------------------------------------------
__global__ __launch_bounds__(256) void kg16_kernel(
    const unsigned short* __restrict__ x, const unsigned short* __restrict__ Wkg1,
    float* __restrict__ kg16)
{
    __shared__ __align__(16) float xs[2048];
    __shared__ float part[16][17];
    const int m = blockIdx.x;
    const int tid = threadIdx.x;
    us8 xv = *reinterpret_cast<const us8*>(x + (size_t)m * 2048 + tid * 8);
#pragma unroll
    for (int i = 0; i < 8; ++i) xs[tid * 8 + i] = b2f(xv[i]);
    __syncthreads();
    const int n = tid & 15, sl = tid >> 4;
    const unsigned short* wrow = Wkg1 + (size_t)n * 2048 + sl * 128;
    float s = 0.f;
#pragma unroll 8
    for (int i = 0; i < 128; ++i) s += xs[sl * 128 + i] * b2f(wrow[i]);
    part[sl][n] = s;
    __syncthreads();
    if (tid < 16) {
        float accv = 0.f;
#pragma unroll
        for (int g = 0; g < 16; ++g) accv += part[g][tid];
        kg16[m * 16 + tid] = accv;
    }
}

__global__ __launch_bounds__(256) void gate_kernel(
    const float* __restrict__ kg16, const unsigned short* __restrict__ Wkg2,
    const unsigned short* __restrict__ bkg2, float* __restrict__ Ag)
{
    __shared__ float kgs[64][17];
    const int blk = blockIdx.x;
    const int b = blk >> 5, ch = blk & 31;
    const int tid = threadIdx.x;
    {
        const int t = tid >> 2, j0 = (tid & 3) * 4;
        fx4 vv = *reinterpret_cast<const fx4*>(
            kg16 + ((size_t)(b * 2048 + ch * 64 + t)) * 16 + j0);
#pragma unroll
        for (int i = 0; i < 4; ++i) kgs[t][j0 + i] = vv[i];
    }
    const int c0 = tid * 4;
    float w[4][16], bb[4];
#pragma unroll
    for (int qi = 0; qi < 4; ++qi) {
#pragma unroll
        for (int j = 0; j < 16; ++j) w[qi][j] = b2f(Wkg2[(size_t)(c0 + qi) * 16 + j]);
        bb[qi] = b2f(bkg2[c0 + qi]);
    }
    __syncthreads();
    const int h = c0 >> 6, d0 = c0 & 63;
    float* outbase = Ag + ((size_t)(b * 16 + h) * 2048 + ch * 64) * 64 + d0;
    float accq[4] = {0.f, 0.f, 0.f, 0.f};
    for (int t = 0; t < 64; ++t) {
        fx4 st;
#pragma unroll
        for (int qi = 0; qi < 4; ++qi) {
            float z = bb[qi];
#pragma unroll
            for (int j = 0; j < 16; ++j) z += kgs[t][j] * w[qi][j];
            accq[qi] += logsigmoidf(z) * 0.0625f;
            st[qi] = accq[qi];
        }
        *reinterpret_cast<fx4*>(outbase + (size_t)t * 64) = st;
    }
}

// ---------------------------------------------------------------------------
// pass1 (MFMA): T^T[j][d] = sum_s v[s,j] * k[s,d]*exp(A63[d]-A[s][d])
// A-operand = vT [j][s], B-operand = kT [d][s]; both swizzled 64-col tiles.
// ---------------------------------------------------------------------------
__global__ __launch_bounds__(256) void pass1_kernel(
    const unsigned short* __restrict__ k, const unsigned short* __restrict__ v,
    const float* __restrict__ Ag, float* __restrict__ Tc)
{
    __shared__ __align__(16) unsigned short kT[64 * 64];   // [d][s]
    __shared__ __align__(16) unsigned short vT[128 * 64];  // [j][s]

    const int blk = blockIdx.x;
    const int ch = blk & 31, bh = blk >> 5;
    const int b = bh >> 4, h = bh & 15;
    const int tid = threadIdx.x;
    const int lane = tid & 63, w = tid >> 6;
    const int quad = lane >> 4, l15 = lane & 15;

    const float* Abase = Ag + ((size_t)bh * 2048 + ch * 64) * 64;
    const unsigned short* kbase = k + ((size_t)(b * 2048 + ch * 64)) * 1024 + h * 64;
    const unsigned short* vbase = v + ((size_t)(b * 2048 + ch * 64)) * 2048 + h * 128;

    // stage kT: thread handles row s = tid>>2, 16 d starting at (tid&3)*16
    {
        const int s = tid >> 2, d0 = (tid & 3) * 16;
        float av[16], a63[16];
        *(fx4*)(av)      = *(const fx4*)(Abase + (size_t)s * 64 + d0);
        *(fx4*)(av + 4)  = *(const fx4*)(Abase + (size_t)s * 64 + d0 + 4);
        *(fx4*)(av + 8)  = *(const fx4*)(Abase + (size_t)s * 64 + d0 + 8);
        *(fx4*)(av + 12) = *(const fx4*)(Abase + (size_t)s * 64 + d0 + 12);
        *(fx4*)(a63)      = *(const fx4*)(Abase + (size_t)63 * 64 + d0);
        *(fx4*)(a63 + 4)  = *(const fx4*)(Abase + (size_t)63 * 64 + d0 + 4);
        *(fx4*)(a63 + 8)  = *(const fx4*)(Abase + (size_t)63 * 64 + d0 + 8);
        *(fx4*)(a63 + 12) = *(const fx4*)(Abase + (size_t)63 * 64 + d0 + 12);
        us8 k0v = *(const us8*)(kbase + (size_t)s * 1024 + d0);
        us8 k1v = *(const us8*)(kbase + (size_t)s * 1024 + d0 + 8);
#pragma unroll
        for (int e = 0; e < 8; ++e) {
            kT[sw_idx(d0 + e, s)]     = f2b(b2f(k0v[e]) * __expf(a63[e] - av[e]));
            kT[sw_idx(d0 + 8 + e, s)] = f2b(b2f(k1v[e]) * __expf(a63[8 + e] - av[8 + e]));
        }
    }
    // stage vT: thread handles row s = tid>>2, 32 j starting at (tid&3)*32
    {
        const int s = tid >> 2, j0 = (tid & 3) * 32;
#pragma unroll
        for (int g2 = 0; g2 < 4; ++g2) {
            us8 vv = *(const us8*)(vbase + (size_t)s * 2048 + j0 + g2 * 8);
#pragma unroll
            for (int e = 0; e < 8; ++e) vT[sw_idx(j0 + g2 * 8 + e, s)] = vv[e];
        }
    }
    __syncthreads();

    // B-frags (kT) shared across both m-tiles
    bf16x8 bk[4][2];
#pragma unroll
    for (int nt = 0; nt < 4; ++nt) {
        bk[nt][0] = frag64(kT, nt * 16 + l15, quad);
        bk[nt][1] = frag64(kT, nt * 16 + l15, quad + 4);
    }
    fx4 acc[2][4];
#pragma unroll
    for (int mi = 0; mi < 2; ++mi)
#pragma unroll
        for (int nt = 0; nt < 4; ++nt) acc[mi][nt] = fx4{0.f, 0.f, 0.f, 0.f};
#pragma unroll
    for (int mi = 0; mi < 2; ++mi) {
        const int mrow = (w * 2 + mi) * 16 + l15;
        bf16x8 av0 = frag64(vT, mrow, quad);
        bf16x8 av1 = frag64(vT, mrow, quad + 4);
#pragma unroll
        for (int nt = 0; nt < 4; ++nt) {
            acc[mi][nt] = __builtin_amdgcn_mfma_f32_16x16x32_bf16(av0, bk[nt][0], acc[mi][nt], 0, 0, 0);
            acc[mi][nt] = __builtin_amdgcn_mfma_f32_16x16x32_bf16(av1, bk[nt][1], acc[mi][nt], 0, 0, 0);
        }
    }
    float* tb = Tc + (size_t)blk * 8192;
#pragma unroll
    for (int mi = 0; mi < 2; ++mi)
#pragma unroll
        for (int nt = 0; nt < 4; ++nt)
#pragma unroll
            for (int r = 0; r < 4; ++r) {
                const int j = (w * 2 + mi) * 16 + quad * 4 + r;
                const int d = nt * 16 + l15;
                tb[(size_t)j * 64 + d] = acc[mi][nt][r];
            }
}

// ---------------------------------------------------------------------------
// combine: scan 32 chunks; TS holds T^T [j][d] on entry, S_start^T on exit.
// ---------------------------------------------------------------------------
__global__ __launch_bounds__(256) void combine_kernel(
    float* __restrict__ TS, const float* __restrict__ Ag)
{
    const int blk = blockIdx.x;       // bh*4 + js
    const int js = blk & 3, bh = blk >> 2;
    const int tid = threadIdx.x;
    const int j = js * 32 + (tid >> 3), d0 = (tid & 7) * 8;
    float S[8] = {0.f, 0.f, 0.f, 0.f, 0.f, 0.f, 0.f, 0.f};
    const float* Abase = Ag + (size_t)bh * 2048 * 64;
    for (int c = 0; c < 32; ++c) {
        float* p = TS + ((size_t)(bh * 32 + c)) * 8192 + (size_t)j * 64 + d0;
        fx4 t1 = *(const fx4*)p;
        fx4 t2 = *(const fx4*)(p + 4);
        fx4 s1, s2;
#pragma unroll
        for (int e = 0; e < 4; ++e) { s1[e] = S[e]; s2[e] = S[4 + e]; }
        *(fx4*)p = s1;
        *(fx4*)(p + 4) = s2;
        const float* ab = Abase + ((size_t)c * 64 + 63) * 64 + d0;
        fx4 a1 = *(const fx4*)ab;
        fx4 a2 = *(const fx4*)(ab + 4);
#pragma unroll
        for (int e = 0; e < 4; ++e) {
            S[e]     = S[e]     * __expf(a1[e]) + t1[e];
            S[4 + e] = S[4 + e] * __expf(a2[e]) + t2[e];
        }
    }
}

// ---------------------------------------------------------------------------
// pass2 (MFMA): P = tri(Q~K~^T); O = Q~@S^T(hi/lo) + P@V; LN; silu-gate; y.
// ---------------------------------------------------------------------------
__global__ __launch_bounds__(256) void pass2_kernel(
    const unsigned short* __restrict__ q, const unsigned short* __restrict__ k,
    const unsigned short* __restrict__ v, const float* __restrict__ Ag,
    const float* __restrict__ Sst, const unsigned short* __restrict__ sg,
    unsigned short* __restrict__ y)
{
    __shared__ __align__(16) unsigned short qs[64 * 64];    // q~ [t][d]
    __shared__ __align__(16) unsigned short ksh[64 * 64];   // k~ [s][d]
    __shared__ __align__(16) unsigned short vT[128 * 64];   // v^T [j][s]
    __shared__ __align__(16) unsigned short Pb[64 * 64];    // P [t][s] bf16
    __shared__ __align__(16) unsigned short Ob[64 * 144];   // normalized O [t][j]

    const int blk = blockIdx.x;
    const int ch = blk & 31, bh = blk >> 5;
    const int b = bh >> 4, h = bh & 15;
    const int tid = threadIdx.x;
    const int lane = tid & 63, w = tid >> 6;
    const int quad = lane >> 4, l15 = lane & 15;

    const float* Abase = Ag + ((size_t)bh * 2048 + ch * 64) * 64;
    const unsigned short* qbase = q + ((size_t)(b * 2048 + ch * 64)) * 1024 + h * 64;
    const unsigned short* kbase = k + ((size_t)(b * 2048 + ch * 64)) * 1024 + h * 64;
    const unsigned short* vbase = v + ((size_t)(b * 2048 + ch * 64)) * 2048 + h * 128;

    // stage q~ and k~
    {
        const int t = tid >> 2, d0 = (tid & 3) * 16;
        float av[16];
        *(fx4*)(av)      = *(const fx4*)(Abase + (size_t)t * 64 + d0);
        *(fx4*)(av + 4)  = *(const fx4*)(Abase + (size_t)t * 64 + d0 + 4);
        *(fx4*)(av + 8)  = *(const fx4*)(Abase + (size_t)t * 64 + d0 + 8);
        *(fx4*)(av + 12) = *(const fx4*)(Abase + (size_t)t * 64 + d0 + 12);
        us8 q0 = *(const us8*)(qbase + (size_t)t * 1024 + d0);
        us8 q1 = *(const us8*)(qbase + (size_t)t * 1024 + d0 + 8);
        us8 k0 = *(const us8*)(kbase + (size_t)t * 1024 + d0);
        us8 k1 = *(const us8*)(kbase + (size_t)t * 1024 + d0 + 8);
        us8 qo0, qo1, ko0, ko1;
#pragma unroll
        for (int e = 0; e < 8; ++e) {
            float e0 = __expf(av[e]),     n0 = __expf(-av[e]);
            float e1 = __expf(av[8 + e]), n1 = __expf(-av[8 + e]);
            qo0[e] = f2b(b2f(q0[e]) * e0);
            qo1[e] = f2b(b2f(q1[e]) * e1);
            ko0[e] = f2b(b2f(k0[e]) * n0);
            ko1[e] = f2b(b2f(k1[e]) * n1);
        }
        const int c0 = d0 >> 3, t7 = t & 7;
        *(us8*)(qs  + t * 64 + ((c0 ^ t7) << 3))       = qo0;
        *(us8*)(qs  + t * 64 + (((c0 + 1) ^ t7) << 3)) = qo1;
        *(us8*)(ksh + t * 64 + ((c0 ^ t7) << 3))       = ko0;
        *(us8*)(ksh + t * 64 + (((c0 + 1) ^ t7) << 3)) = ko1;
    }
    // stage v^T
    {
        const int s = tid >> 2, j0 = (tid & 3) * 32;
#pragma unroll
        for (int g2 = 0; g2 < 4; ++g2) {
            us8 vv = *(const us8*)(vbase + (size_t)s * 2048 + j0 + g2 * 8);
#pragma unroll
            for (int e = 0; e < 8; ++e) vT[sw_idx(j0 + g2 * 8 + e, s)] = vv[e];
        }
    }
    __syncthreads();

    // MFMA1: P rows w*16..w*16+15, all 64 cols
    bf16x8 aQ0 = frag64(qs, w * 16 + l15, quad);
    bf16x8 aQ1 = frag64(qs, w * 16 + l15, quad + 4);
    fx4 accP[4];
#pragma unroll
    for (int nt = 0; nt < 4; ++nt) accP[nt] = fx4{0.f, 0.f, 0.f, 0.f};
#pragma unroll
    for (int nt = 0; nt < 4; ++nt) {
        bf16x8 bK0 = frag64(ksh, nt * 16 + l15, quad);
        bf16x8 bK1 = frag64(ksh, nt * 16 + l15, quad + 4);
        accP[nt] = __builtin_amdgcn_mfma_f32_16x16x32_bf16(aQ0, bK0, accP[nt], 0, 0, 0);
        accP[nt] = __builtin_amdgcn_mfma_f32_16x16x32_bf16(aQ1, bK1, accP[nt], 0, 0, 0);
    }
    // causal mask + bf16 -> Pb
#pragma unroll
    for (int nt = 0; nt < 4; ++nt)
#pragma unroll
        for (int r = 0; r < 4; ++r) {
            const int t = w * 16 + quad * 4 + r;
            const int s = nt * 16 + l15;
            Pb[sw_idx(t, s)] = f2b((s <= t) ? accP[nt][r] : 0.0f);
        }
    __syncthreads();

    // MFMA2: O rows w*16.., 128 cols (8 n-tiles)
    bf16x8 aP0 = frag64(Pb, w * 16 + l15, quad);
    bf16x8 aP1 = frag64(Pb, w * 16 + l15, quad + 4);
    const float* ST = Sst + (size_t)blk * 8192;
    fx4 accO[8];
#pragma unroll
    for (int nt = 0; nt < 8; ++nt) accO[nt] = fx4{0.f, 0.f, 0.f, 0.f};
#pragma unroll
    for (int nt = 0; nt < 8; ++nt) {
        const int j = nt * 16 + l15;
        bf16x8 bV0 = frag64(vT, j, quad);
        bf16x8 bV1 = frag64(vT, j, quad + 4);
        const float* sp = ST + (size_t)j * 64 + quad * 8;
        fx4 s0a = *(const fx4*)(sp),      s0b = *(const fx4*)(sp + 4);
        fx4 s1a = *(const fx4*)(sp + 32), s1b = *(const fx4*)(sp + 36);
        us8 hi0u, lo0u, hi1u, lo1u;
#pragma unroll
        for (int e = 0; e < 4; ++e) {
            unsigned short hh;
            hh = f2b(s0a[e]); hi0u[e] = hh;     lo0u[e]     = f2b(s0a[e] - b2f(hh));
            hh = f2b(s0b[e]); hi0u[4 + e] = hh; lo0u[4 + e] = f2b(s0b[e] - b2f(hh));
            hh = f2b(s1a[e]); hi1u[e] = hh;     lo1u[e]     = f2b(s1a[e] - b2f(hh));
            hh = f2b(s1b[e]); hi1u[4 + e] = hh; lo1u[4 + e] = f2b(s1b[e] - b2f(hh));
        }
        bf16x8 hi0 = __builtin_bit_cast(bf16x8, hi0u);
        bf16x8 lo0 = __builtin_bit_cast(bf16x8, lo0u);
        bf16x8 hi1 = __builtin_bit_cast(bf16x8, hi1u);
        bf16x8 lo1 = __builtin_bit_cast(bf16x8, lo1u);
        accO[nt] = __builtin_amdgcn_mfma_f32_16x16x32_bf16(aP0, bV0, accO[nt], 0, 0, 0);
        accO[nt] = __builtin_amdgcn_mfma_f32_16x16x32_bf16(aP1, bV1, accO[nt], 0, 0, 0);
        accO[nt] = __builtin_amdgcn_mfma_f32_16x16x32_bf16(aQ0, hi0, accO[nt], 0, 0, 0);
        accO[nt] = __builtin_amdgcn_mfma_f32_16x16x32_bf16(aQ1, hi1, accO[nt], 0, 0, 0);
        accO[nt] = __builtin_amdgcn_mfma_f32_16x16x32_bf16(aQ0, lo0, accO[nt], 0, 0, 0);
        accO[nt] = __builtin_amdgcn_mfma_f32_16x16x32_bf16(aQ1, lo1, accO[nt], 0, 0, 0);
    }

    // LayerNorm over j (128) per row: reduce own 8 + shfl over l15
    float sum1[4] = {0.f, 0.f, 0.f, 0.f}, sum2[4] = {0.f, 0.f, 0.f, 0.f};
#pragma unroll
    for (int nt = 0; nt < 8; ++nt)
#pragma unroll
        for (int r = 0; r < 4; ++r) {
            float ov = accO[nt][r];
            sum1[r] += ov;
            sum2[r] += ov * ov;
        }
#pragma unroll
    for (int m = 1; m < 16; m <<= 1)
#pragma unroll
        for (int r = 0; r < 4; ++r) {
            sum1[r] += __shfl_xor(sum1[r], m, 64);
            sum2[r] += __shfl_xor(sum2[r], m, 64);
        }
    float mu[4], inv[4];
#pragma unroll
    for (int r = 0; r < 4; ++r) {
        mu[r] = sum1[r] * (1.0f / 128.0f);
        float var = sum2[r] * (1.0f / 128.0f) - mu[r] * mu[r];
        inv[r] = rsqrtf(var + 1e-5f);
    }
#pragma unroll
    for (int nt = 0; nt < 8; ++nt)
#pragma unroll
        for (int r = 0; r < 4; ++r) {
            const int t = w * 16 + quad * 4 + r;
            Ob[t * 144 + nt * 16 + l15] = f2b((accO[nt][r] - mu[r]) * inv[r]);
        }
    __syncthreads();

    // gated coalesced output
    {
        const int t2 = tid >> 2, jg = (tid & 3) * 32;
        const size_t obase = ((size_t)(b * 2048 + ch * 64 + t2)) * 2048 + h * 128 + jg;
#pragma unroll
        for (int g2 = 0; g2 < 4; ++g2) {
            us8 ob = *(const us8*)(Ob + t2 * 144 + jg + g2 * 8);
            us8 gv = *(const us8*)(sg + obase + g2 * 8);
            us8 ov;
#pragma unroll
            for (int e = 0; e < 8; ++e) ov[e] = f2b(b2f(gv[e]) * b2f(ob[e]));
            *(us8*)(y + obase + g2 * 8) = ov;
        }
    }
}

// ---------------------------------------------------------------------------
extern "C" void kernel_launch(void* const* d_in, const int* in_sizes, int n_in,
                              void* d_out, int out_size, void* d_ws, size_t ws_size,
                              hipStream_t stream)
{
    unsigned short* out = (unsigned short*)d_out;

    char* ws = (char*)d_ws;
    size_t off = 0;
    auto alloc = [&](size_t bytes) -> void* {
        void* p = ws + off;
        off += (bytes + 255) & ~(size_t)255;
        return p;
    };
    unsigned short* xb    = (unsigned short*)alloc((size_t)4096 * 2048 * 2);
    unsigned short* Wqb   = (unsigned short*)alloc((size_t)1024 * 2048 * 2);
    unsigned short* Wkb   = (unsigned short*)alloc((size_t)1024 * 2048 * 2);
    unsigned short* Wkg1b = (unsigned short*)alloc((size_t)16 * 2048 * 2);
    unsigned short* Wkg2b = (unsigned short*)alloc((size_t)1024 * 16 * 2);
    unsigned short* bkg2b = (unsigned short*)alloc((size_t)1024 * 2);
    unsigned short* Wvb   = (unsigned short*)alloc((size_t)2048 * 2048 * 2);
    unsigned short* Wgb   = (unsigned short*)alloc((size_t)2048 * 2048 * 2);
    unsigned short* bgb   = (unsigned short*)alloc((size_t)2048 * 2);
    unsigned short* Wob   = (unsigned short*)alloc((size_t)2048 * 2048 * 2);
    unsigned short* qb   = (unsigned short*)alloc((size_t)4096 * 1024 * 2);
    unsigned short* kb   = (unsigned short*)alloc((size_t)4096 * 1024 * 2);
    unsigned short* vb   = (unsigned short*)alloc((size_t)4096 * 2048 * 2);
    unsigned short* sgb  = (unsigned short*)alloc((size_t)4096 * 2048 * 2);
    unsigned short* yb   = (unsigned short*)alloc((size_t)4096 * 2048 * 2);
    float*          kg16 = (float*)alloc((size_t)4096 * 16 * 4);
    float*          Agb  = (float*)alloc((size_t)4096 * 1024 * 4);
    float*          TS   = (float*)alloc((size_t)1024 * 8192 * 4);
    int*            flag = (int*)alloc(256);

    detect_kernel<<<1, 256, 0, stream>>>((const unsigned int*)d_in[0], flag);

    struct { const void* src; unsigned short* dst; int n; } cv[10] = {
        { d_in[0], xb,    4096 * 2048 },
        { d_in[1], Wqb,   1024 * 2048 },
        { d_in[2], Wkb,   1024 * 2048 },
        { d_in[3], Wkg1b, 16 * 2048 },
        { d_in[4], Wkg2b, 1024 * 16 },
        { d_in[5], bkg2b, 1024 },
        { d_in[6], Wvb,   2048 * 2048 },
        { d_in[7], Wgb,   2048 * 2048 },
        { d_in[8], bgb,   2048 },
        { d_in[9], Wob,   2048 * 2048 },
    };
    for (int i = 0; i < 10; ++i) {
        int nthr = cv[i].n / 4;
        convert_kernel<<<(nthr + 255) / 256, 256, 0, stream>>>(
            cv[i].src, cv[i].dst, cv[i].n, flag);
    }

    const float SCALE = 0.08838834764831845f;  // 128**-0.5

    gemm_bt_kernel<<<dim3(8, 32),  256, 0, stream>>>(xb, Wqb, qb,  4096, 1024, 2048, 1.0f,  nullptr, 0, nullptr);
    gemm_bt_kernel<<<dim3(8, 32),  256, 0, stream>>>(xb, Wkb, kb,  4096, 1024, 2048, SCALE, nullptr, 0, nullptr);
    gemm_bt_kernel<<<dim3(16, 32), 256, 0, stream>>>(xb, Wvb, vb,  4096, 2048, 2048, 1.0f,  nullptr, 0, nullptr);
    gemm_bt_kernel<<<dim3(16, 32), 256, 0, stream>>>(xb, Wgb, sgb, 4096, 2048, 2048, 1.0f,  bgb,     1, nullptr);
    kg16_kernel<<<4096, 256, 0, stream>>>(xb, Wkg1b, kg16);
    gate_kernel<<<64, 256, 0, stream>>>(kg16, Wkg2b, bkg2b, Agb);
    pass1_kernel<<<1024, 256, 0, stream>>>(kb, vb, Agb, TS);
    combine_kernel<<<128, 256, 0, stream>>>(TS, Agb);
    pass2_kernel<<<1024, 256, 0, stream>>>(qb, kb, vb, Agb, TS, sgb, yb);
    gemm_bt_kernel<<<dim3(16, 32), 256, 0, stream>>>(yb, Wob, out, 4096, 2048, 2048, 1.0f, nullptr, 0, flag);
}

// Round 4
// 460.815 us; speedup vs baseline: 1.4135x; 1.2216x over previous
//
#include <hip/hip_runtime.h>
#include <hip/hip_bf16.h>

using bf16x8 = __attribute__((ext_vector_type(8))) __bf16;
using fx4    = __attribute__((ext_vector_type(4))) float;
using us4    = __attribute__((ext_vector_type(4))) unsigned short;
using us8    = __attribute__((ext_vector_type(8))) unsigned short;

__device__ __forceinline__ float b2f(unsigned short u) {
    unsigned int x = ((unsigned int)u) << 16;
    return __builtin_bit_cast(float, x);
}
__device__ __forceinline__ unsigned short f2b(float f) {
    __hip_bfloat16 h = __float2bfloat16(f);
    return __builtin_bit_cast(unsigned short, h);
}
__device__ __forceinline__ float logsigmoidf(float z) {
    return fminf(z, 0.0f) - log1pf(expf(-fabsf(z)));
}

// async 16B/lane global->LDS (dest = wave-uniform base + lane*16)
__device__ __forceinline__ void gl_lds16(const unsigned short* g, unsigned short* l) {
    __builtin_amdgcn_global_load_lds(
        (const __attribute__((address_space(1))) void*)g,
        (__attribute__((address_space(3))) void*)l, 16, 0, 0);
}

// 64-col bf16 LDS tile, 8-elem chunks XOR-swizzled by row&7 (2-way alias = free)
__device__ __forceinline__ bf16x8 frag64(const unsigned short* base, int row, int cq) {
    return *reinterpret_cast<const bf16x8*>(base + row * 64 + (((cq ^ (row & 7)) << 3)));
}
__device__ __forceinline__ int sw_idx(int row, int col) {
    return row * 64 + ((((col >> 3) ^ (row & 7)) << 3)) + (col & 7);
}

// ---------------------------------------------------------------------------
// dtype detect (flag=1 -> fp32 inputs)
// ---------------------------------------------------------------------------
__global__ __launch_bounds__(256) void detect_kernel(
    const unsigned int* __restrict__ x, int* __restrict__ flag)
{
    __shared__ int bad[256];
    const int t = threadIdx.x;
    int b = 0;
#pragma unroll
    for (int i = 0; i < 16; ++i) {
        unsigned int w = x[t * 16 + i];
        float v = b2f((unsigned short)(w & 0xFFFFu));
        if (!(fabsf(v) < 1.0e6f)) b = 1;
    }
    bad[t] = b;
    __syncthreads();
    for (int s = 128; s > 0; s >>= 1) {
        if (t < s) bad[t] |= bad[t + s];
        __syncthreads();
    }
    if (t == 0) flag[0] = bad[0];
}

// ---------------------------------------------------------------------------
// fused convert: all 10 inputs -> bf16 in one launch. Sizes are static.
// Each block handles 1024 elems of one segment (all sizes divide 1024).
// ---------------------------------------------------------------------------
struct CvtArgs {
    const void* src[10];
    unsigned short* dst[10];
};

__global__ __launch_bounds__(256) void convert_all_kernel(
    CvtArgs a, const int* __restrict__ flag)
{
    // block-prefix per segment (1024 elems per block):
    // x:8192, Wq:2048, Wk:2048, Wkg1:32, Wkg2:16, bkg2:1, Wv:4096, Wg:4096, bg:2, Wo:4096
    const int pref[11] = {0, 8192, 10240, 12288, 12320, 12336, 12337,
                          16433, 20529, 20531, 24627};
    const int blk = blockIdx.x;
    int s = 0;
#pragma unroll
    for (int i = 1; i < 10; ++i) s += (blk >= pref[i]) ? 1 : 0;
    const int i0 = (blk - pref[s]) * 1024 + threadIdx.x * 4;
    if (*flag) {
        const float* sp = (const float*)a.src[s];
        fx4 v = *reinterpret_cast<const fx4*>(sp + i0);
        us4 r;
#pragma unroll
        for (int e = 0; e < 4; ++e) r[e] = f2b(v[e]);
        *reinterpret_cast<us4*>(a.dst[s] + i0) = r;
    } else {
        const unsigned short* sp = (const unsigned short*)a.src[s];
        *reinterpret_cast<us4*>(a.dst[s] + i0) =
            *reinterpret_cast<const us4*>(sp + i0);
    }
}

// ---------------------------------------------------------------------------
// GEMM (m97 structure): BK=64, XOR-swizzled unpadded LDS, global_load_lds.
// C = act(alpha(col) * (A@W^T) + bias); alpha = (col<asplit)?alpha_lo:alpha_hi
// ---------------------------------------------------------------------------
__global__ __launch_bounds__(256) void gemm_bt_kernel(
    const unsigned short* __restrict__ A, const unsigned short* __restrict__ W,
    unsigned short* __restrict__ C, int M, int N, int K,
    float alpha_lo, float alpha_hi, int asplit,
    const unsigned short* __restrict__ bias, int act,
    const int* __restrict__ oflag)
{
    __shared__ __align__(16) unsigned short As[128 * 64];
    __shared__ __align__(16) unsigned short Bs[128 * 64];

    const int tid  = threadIdx.x;
    const int lane = tid & 63, wid = tid >> 6;
    const int quad = lane >> 4, l15 = lane & 15;
    const int wm = (wid & 1) * 64, wn = (wid >> 1) * 64;
    const int m0 = blockIdx.y * 128, n0 = blockIdx.x * 128;

    fx4 acc[4][4];
#pragma unroll
    for (int i = 0; i < 4; ++i)
#pragma unroll
        for (int j = 0; j < 4; ++j) acc[i][j] = fx4{0.f, 0.f, 0.f, 0.f};

    const int srow = lane >> 3;
    const int g8   = ((lane & 7) ^ srow) * 8;
    const int c8   = (lane & 7) * 8;
    const unsigned short* Ab = A + (size_t)m0 * K;
    const unsigned short* Wb = W + (size_t)n0 * K;

    for (int k0 = 0; k0 < K; k0 += 64) {
#pragma unroll
        for (int p = 0; p < 4; ++p) {
            const int la  = wid * 4 + p;
            const int row = la * 8 + srow;
            gl_lds16(Ab + (size_t)row * K + k0 + g8, As + row * 64 + c8);
            gl_lds16(Wb + (size_t)row * K + k0 + g8, Bs + row * 64 + c8);
        }
        __syncthreads();
#pragma unroll
        for (int ks = 0; ks < 2; ++ks) {
            const int cq = quad + ks * 4;
            bf16x8 af[4], bfr[4];
#pragma unroll
            for (int mt = 0; mt < 4; ++mt) af[mt] = frag64(As, wm + mt * 16 + l15, cq);
#pragma unroll
            for (int nt = 0; nt < 4; ++nt) bfr[nt] = frag64(Bs, wn + nt * 16 + l15, cq);
#pragma unroll
            for (int mt = 0; mt < 4; ++mt)
#pragma unroll
                for (int nt = 0; nt < 4; ++nt)
                    acc[mt][nt] = __builtin_amdgcn_mfma_f32_16x16x32_bf16(
                        af[mt], bfr[nt], acc[mt][nt], 0, 0, 0);
        }
        __syncthreads();
    }

    const int f32out = oflag ? *oflag : 0;
#pragma unroll
    for (int nt = 0; nt < 4; ++nt) {
        const int ncol = n0 + wn + nt * 16 + l15;
        const float av = (ncol < asplit) ? alpha_lo : alpha_hi;
        const float bv = bias ? b2f(bias[ncol]) : 0.0f;
#pragma unroll
        for (int mt = 0; mt < 4; ++mt) {
#pragma unroll
            for (int r = 0; r < 4; ++r) {
                const int mrow = m0 + wm + mt * 16 + quad * 4 + r;
                float val = acc[mt][nt][r] * av + bv;
                if (act) val = val / (1.0f + __expf(-val));
                const size_t idx = (size_t)mrow * N + ncol;
                if (f32out) ((float*)C)[idx] = val;
                else        C[idx] = f2b(val);
            }
        }
    }
}

// ---------------------------------------------------------------------------
// gate1 (fused kg16 + projection + logsigmoid, fully parallel):
// block = one row m (b*2048+l).  Ag <- logsigmoid(kg)/16  (NOT yet cumsummed)
// ---------------------------------------------------------------------------
__global__ __launch_bounds__(256) void gate1_kernel(
    const unsigned short* __restrict__ x, const unsigned short* __restrict__ Wkg1,
    const unsigned short* __restrict__ Wkg2, const unsigned short* __restrict__ bkg2,
    float* __restrict__ Ag)
{
    __shared__ __align__(16) float xs[2048];
    __shared__ float part[16][17];
    __shared__ float kgrow[16];
    const int m = blockIdx.x;
    const int tid = threadIdx.x;
    us8 xv = *reinterpret_cast<const us8*>(x + (size_t)m * 2048 + tid * 8);
#pragma unroll
    for (int i = 0; i < 8; ++i) xs[tid * 8 + i] = b2f(xv[i]);
    __syncthreads();
    {
        const int n = tid & 15, sl = tid >> 4;
        const unsigned short* wrow = Wkg1 + (size_t)n * 2048 + sl * 128;
        float s = 0.f;
#pragma unroll 8
        for (int i = 0; i < 128; ++i) s += xs[sl * 128 + i] * b2f(wrow[i]);
        part[sl][n] = s;
    }
    __syncthreads();
    if (tid < 16) {
        float accv = 0.f;
#pragma unroll
        for (int g = 0; g < 16; ++g) accv += part[g][tid];
        kgrow[tid] = accv;
    }
    __syncthreads();
    float kr[16];
#pragma unroll
    for (int j = 0; j < 16; ++j) kr[j] = kgrow[j];
    const int b = m >> 11, l = m & 2047;
    const int c0 = tid * 4;
    const int h = c0 >> 6, d0 = c0 & 63;
    fx4 gv;
#pragma unroll
    for (int qi = 0; qi < 4; ++qi) {
        const int c = c0 + qi;
        us8 w0 = *reinterpret_cast<const us8*>(Wkg2 + (size_t)c * 16);
        us8 w1 = *reinterpret_cast<const us8*>(Wkg2 + (size_t)c * 16 + 8);
        float z = b2f(bkg2[c]);
#pragma unroll
        for (int j = 0; j < 8; ++j) z += kr[j] * b2f(w0[j]) + kr[8 + j] * b2f(w1[j]);
        gv[qi] = logsigmoidf(z) * 0.0625f;
    }
    *reinterpret_cast<fx4*>(Ag + ((size_t)(b * 16 + h) * 2048 + l) * 64 + d0) = gv;
}

// ---------------------------------------------------------------------------
// gate2: in-chunk (64) inclusive cumsum along t, in place.
// thread = (bh, ch, d); 64 independent loads pipelined, then scan.
// ---------------------------------------------------------------------------
__global__ __launch_bounds__(256) void gate2_kernel(float* __restrict__ Ag)
{
    const int gidx = blockIdx.x * 256 + threadIdx.x;   // 65536
    const int d = gidx & 63, ch = (gidx >> 6) & 31, bh = gidx >> 11;
    float* p = Ag + ((size_t)bh * 2048 + ch * 64) * 64 + d;
    float acc = 0.f;
#pragma unroll 8
    for (int t = 0; t < 64; ++t) {
        acc += p[(size_t)t * 64];
        p[(size_t)t * 64] = acc;
    }
}

// ---------------------------------------------------------------------------
// pass1 (MFMA): T^T[j][d] = sum_s v[s,j] * k[s,d]*exp(A63[d]-A[s][d])
// k has row stride kstr (merged qk buffer).
// ---------------------------------------------------------------------------
__global__ __launch_bounds__(256) void pass1_kernel(
    const unsigned short* __restrict__ k, int kstr,
    const unsigned short* __restrict__ v,
    const float* __restrict__ Ag, float* __restrict__ Tc)
{
    __shared__ __align__(16) unsigned short kT[64 * 64];   // [d][s]
    __shared__ __align__(16) unsigned short vT[128 * 64];  // [j][s]

    const int blk = blockIdx.x;
    const int ch = blk & 31, bh = blk >> 5;
    const int b = bh >> 4, h = bh & 15;
    const int tid = threadIdx.x;
    const int lane = tid & 63, w = tid >> 6;
    const int quad = lane >> 4, l15 = lane & 15;

    const float* Abase = Ag + ((size_t)bh * 2048 + ch * 64) * 64;
    const unsigned short* kbase = k + ((size_t)(b * 2048 + ch * 64)) * kstr + h * 64;
    const unsigned short* vbase = v + ((size_t)(b * 2048 + ch * 64)) * 2048 + h * 128;

    {
        const int s = tid >> 2, d0 = (tid & 3) * 16;
        float av[16], a63[16];
        *(fx4*)(av)      = *(const fx4*)(Abase + (size_t)s * 64 + d0);
        *(fx4*)(av + 4)  = *(const fx4*)(Abase + (size_t)s * 64 + d0 + 4);
        *(fx4*)(av + 8)  = *(const fx4*)(Abase + (size_t)s * 64 + d0 + 8);
        *(fx4*)(av + 12) = *(const fx4*)(Abase + (size_t)s * 64 + d0 + 12);
        *(fx4*)(a63)      = *(const fx4*)(Abase + (size_t)63 * 64 + d0);
        *(fx4*)(a63 + 4)  = *(const fx4*)(Abase + (size_t)63 * 64 + d0 + 4);
        *(fx4*)(a63 + 8)  = *(const fx4*)(Abase + (size_t)63 * 64 + d0 + 8);
        *(fx4*)(a63 + 12) = *(const fx4*)(Abase + (size_t)63 * 64 + d0 + 12);
        us8 k0v = *(const us8*)(kbase + (size_t)s * kstr + d0);
        us8 k1v = *(const us8*)(kbase + (size_t)s * kstr + d0 + 8);
#pragma unroll
        for (int e = 0; e < 8; ++e) {
            kT[sw_idx(d0 + e, s)]     = f2b(b2f(k0v[e]) * __expf(a63[e] - av[e]));
            kT[sw_idx(d0 + 8 + e, s)] = f2b(b2f(k1v[e]) * __expf(a63[8 + e] - av[8 + e]));
        }
    }
    {
        const int s = tid >> 2, j0 = (tid & 3) * 32;
#pragma unroll
        for (int g2 = 0; g2 < 4; ++g2) {
            us8 vv = *(const us8*)(vbase + (size_t)s * 2048 + j0 + g2 * 8);
#pragma unroll
            for (int e = 0; e < 8; ++e) vT[sw_idx(j0 + g2 * 8 + e, s)] = vv[e];
        }
    }
    __syncthreads();

    bf16x8 bk[4][2];
#pragma unroll
    for (int nt = 0; nt < 4; ++nt) {
        bk[nt][0] = frag64(kT, nt * 16 + l15, quad);
        bk[nt][1] = frag64(kT, nt * 16 + l15, quad + 4);
    }
    fx4 acc[2][4];
#pragma unroll
    for (int mi = 0; mi < 2; ++mi)
#pragma unroll
        for (int nt = 0; nt < 4; ++nt) acc[mi][nt] = fx4{0.f, 0.f, 0.f, 0.f};
#pragma unroll
    for (int mi = 0; mi < 2; ++mi) {
        const int mrow = (w * 2 + mi) * 16 + l15;
        bf16x8 av0 = frag64(vT, mrow, quad);
        bf16x8 av1 = frag64(vT, mrow, quad + 4);
#pragma unroll
        for (int nt = 0; nt < 4; ++nt) {
            acc[mi][nt] = __builtin_amdgcn_mfma_f32_16x16x32_bf16(av0, bk[nt][0], acc[mi][nt], 0, 0, 0);
            acc[mi][nt] = __builtin_amdgcn_mfma_f32_16x16x32_bf16(av1, bk[nt][1], acc[mi][nt], 0, 0, 0);
        }
    }
    float* tb = Tc + (size_t)blk * 8192;
#pragma unroll
    for (int mi = 0; mi < 2; ++mi)
#pragma unroll
        for (int nt = 0; nt < 4; ++nt)
#pragma unroll
            for (int r = 0; r < 4; ++r) {
                const int j = (w * 2 + mi) * 16 + quad * 4 + r;
                const int d = nt * 16 + l15;
                tb[(size_t)j * 64 + d] = acc[mi][nt][r];
            }
}

// ---------------------------------------------------------------------------
// combine: scan 32 chunks; TS holds T^T [j][d] on entry, S_start^T on exit.
// ---------------------------------------------------------------------------
__global__ __launch_bounds__(256) void combine_kernel(
    float* __restrict__ TS, const float* __restrict__ Ag)
{
    const int blk = blockIdx.x;       // bh*4 + js
    const int js = blk & 3, bh = blk >> 2;
    const int tid = threadIdx.x;
    const int j = js * 32 + (tid >> 3), d0 = (tid & 7) * 8;
    float S[8] = {0.f, 0.f, 0.f, 0.f, 0.f, 0.f, 0.f, 0.f};
    const float* Abase = Ag + (size_t)bh * 2048 * 64;
    for (int c = 0; c < 32; ++c) {
        float* p = TS + ((size_t)(bh * 32 + c)) * 8192 + (size_t)j * 64 + d0;
        fx4 t1 = *(const fx4*)p;
        fx4 t2 = *(const fx4*)(p + 4);
        fx4 s1, s2;
#pragma unroll
        for (int e = 0; e < 4; ++e) { s1[e] = S[e]; s2[e] = S[4 + e]; }
        *(fx4*)p = s1;
        *(fx4*)(p + 4) = s2;
        const float* ab = Abase + ((size_t)c * 64 + 63) * 64 + d0;
        fx4 a1 = *(const fx4*)ab;
        fx4 a2 = *(const fx4*)(ab + 4);
#pragma unroll
        for (int e = 0; e < 4; ++e) {
            S[e]     = S[e]     * __expf(a1[e]) + t1[e];
            S[4 + e] = S[4 + e] * __expf(a2[e]) + t2[e];
        }
    }
}

// ---------------------------------------------------------------------------
// pass2 (MFMA): P = tri(Q~K~^T); O = Q~@S^T(hi/lo) + P@V; LN; silu-gate; y.
// q,k from merged buffer with row stride qkstr.
// ---------------------------------------------------------------------------
__global__ __launch_bounds__(256) void pass2_kernel(
    const unsigned short* __restrict__ q, const unsigned short* __restrict__ k,
    int qkstr,
    const unsigned short* __restrict__ v, const float* __restrict__ Ag,
    const float* __restrict__ Sst, const unsigned short* __restrict__ sg,
    unsigned short* __restrict__ y)
{
    __shared__ __align__(16) unsigned short qs[64 * 64];    // q~ [t][d]
    __shared__ __align__(16) unsigned short ksh[64 * 64];   // k~ [s][d]
    __shared__ __align__(16) unsigned short vT[128 * 64];   // v^T [j][s]
    __shared__ __align__(16) unsigned short Pb[64 * 64];    // P [t][s] bf16
    __shared__ __align__(16) unsigned short Ob[64 * 144];   // normalized O [t][j]

    const int blk = blockIdx.x;
    const int ch = blk & 31, bh = blk >> 5;
    const int b = bh >> 4, h = bh & 15;
    const int tid = threadIdx.x;
    const int lane = tid & 63, w = tid >> 6;
    const int quad = lane >> 4, l15 = lane & 15;

    const float* Abase = Ag + ((size_t)bh * 2048 + ch * 64) * 64;
    const unsigned short* qbase = q + ((size_t)(b * 2048 + ch * 64)) * qkstr + h * 64;
    const unsigned short* kbase = k + ((size_t)(b * 2048 + ch * 64)) * qkstr + h * 64;
    const unsigned short* vbase = v + ((size_t)(b * 2048 + ch * 64)) * 2048 + h * 128;

    {
        const int t = tid >> 2, d0 = (tid & 3) * 16;
        float av[16];
        *(fx4*)(av)      = *(const fx4*)(Abase + (size_t)t * 64 + d0);
        *(fx4*)(av + 4)  = *(const fx4*)(Abase + (size_t)t * 64 + d0 + 4);
        *(fx4*)(av + 8)  = *(const fx4*)(Abase + (size_t)t * 64 + d0 + 8);
        *(fx4*)(av + 12) = *(const fx4*)(Abase + (size_t)t * 64 + d0 + 12);
        us8 q0 = *(const us8*)(qbase + (size_t)t * qkstr + d0);
        us8 q1 = *(const us8*)(qbase + (size_t)t * qkstr + d0 + 8);
        us8 k0 = *(const us8*)(kbase + (size_t)t * qkstr + d0);
        us8 k1 = *(const us8*)(kbase + (size_t)t * qkstr + d0 + 8);
        us8 qo0, qo1, ko0, ko1;
#pragma unroll
        for (int e = 0; e < 8; ++e) {
            float e0 = __expf(av[e]),     n0 = __expf(-av[e]);
            float e1 = __expf(av[8 + e]), n1 = __expf(-av[8 + e]);
            qo0[e] = f2b(b2f(q0[e]) * e0);
            qo1[e] = f2b(b2f(q1[e]) * e1);
            ko0[e] = f2b(b2f(k0[e]) * n0);
            ko1[e] = f2b(b2f(k1[e]) * n1);
        }
        const int c0 = d0 >> 3, t7 = t & 7;
        *(us8*)(qs  + t * 64 + ((c0 ^ t7) << 3))       = qo0;
        *(us8*)(qs  + t * 64 + (((c0 + 1) ^ t7) << 3)) = qo1;
        *(us8*)(ksh + t * 64 + ((c0 ^ t7) << 3))       = ko0;
        *(us8*)(ksh + t * 64 + (((c0 + 1) ^ t7) << 3)) = ko1;
    }
    {
        const int s = tid >> 2, j0 = (tid & 3) * 32;
#pragma unroll
        for (int g2 = 0; g2 < 4; ++g2) {
            us8 vv = *(const us8*)(vbase + (size_t)s * 2048 + j0 + g2 * 8);
#pragma unroll
            for (int e = 0; e < 8; ++e) vT[sw_idx(j0 + g2 * 8 + e, s)] = vv[e];
        }
    }
    __syncthreads();

    bf16x8 aQ0 = frag64(qs, w * 16 + l15, quad);
    bf16x8 aQ1 = frag64(qs, w * 16 + l15, quad + 4);
    fx4 accP[4];
#pragma unroll
    for (int nt = 0; nt < 4; ++nt) accP[nt] = fx4{0.f, 0.f, 0.f, 0.f};
#pragma unroll
    for (int nt = 0; nt < 4; ++nt) {
        bf16x8 bK0 = frag64(ksh, nt * 16 + l15, quad);
        bf16x8 bK1 = frag64(ksh, nt * 16 + l15, quad + 4);
        accP[nt] = __builtin_amdgcn_mfma_f32_16x16x32_bf16(aQ0, bK0, accP[nt], 0, 0, 0);
        accP[nt] = __builtin_amdgcn_mfma_f32_16x16x32_bf16(aQ1, bK1, accP[nt], 0, 0, 0);
    }
#pragma unroll
    for (int nt = 0; nt < 4; ++nt)
#pragma unroll
        for (int r = 0; r < 4; ++r) {
            const int t = w * 16 + quad * 4 + r;
            const int s = nt * 16 + l15;
            Pb[sw_idx(t, s)] = f2b((s <= t) ? accP[nt][r] : 0.0f);
        }
    __syncthreads();

    bf16x8 aP0 = frag64(Pb, w * 16 + l15, quad);
    bf16x8 aP1 = frag64(Pb, w * 16 + l15, quad + 4);
    const float* ST = Sst + (size_t)blk * 8192;
    fx4 accO[8];
#pragma unroll
    for (int nt = 0; nt < 8; ++nt) accO[nt] = fx4{0.f, 0.f, 0.f, 0.f};
#pragma unroll
    for (int nt = 0; nt < 8; ++nt) {
        const int j = nt * 16 + l15;
        bf16x8 bV0 = frag64(vT, j, quad);
        bf16x8 bV1 = frag64(vT, j, quad + 4);
        const float* sp = ST + (size_t)j * 64 + quad * 8;
        fx4 s0a = *(const fx4*)(sp),      s0b = *(const fx4*)(sp + 4);
        fx4 s1a = *(const fx4*)(sp + 32), s1b = *(const fx4*)(sp + 36);
        us8 hi0u, lo0u, hi1u, lo1u;
#pragma unroll
        for (int e = 0; e < 4; ++e) {
            unsigned short hh;
            hh = f2b(s0a[e]); hi0u[e] = hh;     lo0u[e]     = f2b(s0a[e] - b2f(hh));
            hh = f2b(s0b[e]); hi0u[4 + e] = hh; lo0u[4 + e] = f2b(s0b[e] - b2f(hh));
            hh = f2b(s1a[e]); hi1u[e] = hh;     lo1u[e]     = f2b(s1a[e] - b2f(hh));
            hh = f2b(s1b[e]); hi1u[4 + e] = hh; lo1u[4 + e] = f2b(s1b[e] - b2f(hh));
        }
        bf16x8 hi0 = __builtin_bit_cast(bf16x8, hi0u);
        bf16x8 lo0 = __builtin_bit_cast(bf16x8, lo0u);
        bf16x8 hi1 = __builtin_bit_cast(bf16x8, hi1u);
        bf16x8 lo1 = __builtin_bit_cast(bf16x8, lo1u);
        accO[nt] = __builtin_amdgcn_mfma_f32_16x16x32_bf16(aP0, bV0, accO[nt], 0, 0, 0);
        accO[nt] = __builtin_amdgcn_mfma_f32_16x16x32_bf16(aP1, bV1, accO[nt], 0, 0, 0);
        accO[nt] = __builtin_amdgcn_mfma_f32_16x16x32_bf16(aQ0, hi0, accO[nt], 0, 0, 0);
        accO[nt] = __builtin_amdgcn_mfma_f32_16x16x32_bf16(aQ1, hi1, accO[nt], 0, 0, 0);
        accO[nt] = __builtin_amdgcn_mfma_f32_16x16x32_bf16(aQ0, lo0, accO[nt], 0, 0, 0);
        accO[nt] = __builtin_amdgcn_mfma_f32_16x16x32_bf16(aQ1, lo1, accO[nt], 0, 0, 0);
    }

    float sum1[4] = {0.f, 0.f, 0.f, 0.f}, sum2[4] = {0.f, 0.f, 0.f, 0.f};
#pragma unroll
    for (int nt = 0; nt < 8; ++nt)
#pragma unroll
        for (int r = 0; r < 4; ++r) {
            float ov = accO[nt][r];
            sum1[r] += ov;
            sum2[r] += ov * ov;
        }
#pragma unroll
    for (int m = 1; m < 16; m <<= 1)
#pragma unroll
        for (int r = 0; r < 4; ++r) {
            sum1[r] += __shfl_xor(sum1[r], m, 64);
            sum2[r] += __shfl_xor(sum2[r], m, 64);
        }
    float mu[4], inv[4];
#pragma unroll
    for (int r = 0; r < 4; ++r) {
        mu[r] = sum1[r] * (1.0f / 128.0f);
        float var = sum2[r] * (1.0f / 128.0f) - mu[r] * mu[r];
        inv[r] = rsqrtf(var + 1e-5f);
    }
#pragma unroll
    for (int nt = 0; nt < 8; ++nt)
#pragma unroll
        for (int r = 0; r < 4; ++r) {
            const int t = w * 16 + quad * 4 + r;
            Ob[t * 144 + nt * 16 + l15] = f2b((accO[nt][r] - mu[r]) * inv[r]);
        }
    __syncthreads();

    {
        const int t2 = tid >> 2, jg = (tid & 3) * 32;
        const size_t obase = ((size_t)(b * 2048 + ch * 64 + t2)) * 2048 + h * 128 + jg;
#pragma unroll
        for (int g2 = 0; g2 < 4; ++g2) {
            us8 ob = *(const us8*)(Ob + t2 * 144 + jg + g2 * 8);
            us8 gv = *(const us8*)(sg + obase + g2 * 8);
            us8 ov;
#pragma unroll
            for (int e = 0; e < 8; ++e) ov[e] = f2b(b2f(gv[e]) * b2f(ob[e]));
            *(us8*)(y + obase + g2 * 8) = ov;
        }
    }
}

// ---------------------------------------------------------------------------
extern "C" void kernel_launch(void* const* d_in, const int* in_sizes, int n_in,
                              void* d_out, int out_size, void* d_ws, size_t ws_size,
                              hipStream_t stream)
{
    unsigned short* out = (unsigned short*)d_out;

    char* ws = (char*)d_ws;
    size_t off = 0;
    auto alloc = [&](size_t bytes) -> void* {
        void* p = ws + off;
        off += (bytes + 255) & ~(size_t)255;
        return p;
    };
    unsigned short* xb    = (unsigned short*)alloc((size_t)4096 * 2048 * 2);
    unsigned short* Wqkb  = (unsigned short*)alloc((size_t)2048 * 2048 * 2); // [Wq;Wk]
    unsigned short* Wkg1b = (unsigned short*)alloc((size_t)16 * 2048 * 2);
    unsigned short* Wkg2b = (unsigned short*)alloc((size_t)1024 * 16 * 2);
    unsigned short* bkg2b = (unsigned short*)alloc((size_t)1024 * 2);
    unsigned short* Wvb   = (unsigned short*)alloc((size_t)2048 * 2048 * 2);
    unsigned short* Wgb   = (unsigned short*)alloc((size_t)2048 * 2048 * 2);
    unsigned short* bgb   = (unsigned short*)alloc((size_t)2048 * 2);
    unsigned short* Wob   = (unsigned short*)alloc((size_t)2048 * 2048 * 2);
    unsigned short* qkb  = (unsigned short*)alloc((size_t)4096 * 2048 * 2);  // q|k
    unsigned short* vb   = (unsigned short*)alloc((size_t)4096 * 2048 * 2);
    unsigned short* sgb  = (unsigned short*)alloc((size_t)4096 * 2048 * 2);
    unsigned short* yb   = (unsigned short*)alloc((size_t)4096 * 2048 * 2);
    float*          Agb  = (float*)alloc((size_t)4096 * 1024 * 4);
    float*          TS   = (float*)alloc((size_t)1024 * 8192 * 4);
    int*            flag = (int*)alloc(256);

    detect_kernel<<<1, 256, 0, stream>>>((const unsigned int*)d_in[0], flag);

    CvtArgs ca;
    ca.src[0] = d_in[0]; ca.dst[0] = xb;
    ca.src[1] = d_in[1]; ca.dst[1] = Wqkb;                        // Wq -> first half
    ca.src[2] = d_in[2]; ca.dst[2] = Wqkb + (size_t)1024 * 2048;  // Wk -> second half
    ca.src[3] = d_in[3]; ca.dst[3] = Wkg1b;
    ca.src[4] = d_in[4]; ca.dst[4] = Wkg2b;
    ca.src[5] = d_in[5]; ca.dst[5] = bkg2b;
    ca.src[6] = d_in[6]; ca.dst[6] = Wvb;
    ca.src[7] = d_in[7]; ca.dst[7] = Wgb;
    ca.src[8] = d_in[8]; ca.dst[8] = bgb;
    ca.src[9] = d_in[9]; ca.dst[9] = Wob;
    convert_all_kernel<<<24627, 256, 0, stream>>>(ca, flag);

    const float SCALE = 0.08838834764831845f;  // 128**-0.5

    // q|k merged GEMM: cols 0-1023 alpha=1 (q), 1024-2047 alpha=SCALE (k)
    gemm_bt_kernel<<<dim3(16, 32), 256, 0, stream>>>(xb, Wqkb, qkb, 4096, 2048, 2048, 1.0f, SCALE, 1024, nullptr, 0, nullptr);
    gemm_bt_kernel<<<dim3(16, 32), 256, 0, stream>>>(xb, Wvb,  vb,  4096, 2048, 2048, 1.0f, 1.0f, 2048, nullptr, 0, nullptr);
    gemm_bt_kernel<<<dim3(16, 32), 256, 0, stream>>>(xb, Wgb,  sgb, 4096, 2048, 2048, 1.0f, 1.0f, 2048, bgb,     1, nullptr);
    gate1_kernel<<<4096, 256, 0, stream>>>(xb, Wkg1b, Wkg2b, bkg2b, Agb);
    gate2_kernel<<<256, 256, 0, stream>>>(Agb);
    pass1_kernel<<<1024, 256, 0, stream>>>(qkb + 1024, 2048, vb, Agb, TS);
    combine_kernel<<<128, 256, 0, stream>>>(TS, Agb);
    pass2_kernel<<<1024, 256, 0, stream>>>(qkb, qkb + 1024, 2048, vb, Agb, TS, sgb, yb);
    gemm_bt_kernel<<<dim3(16, 32), 256, 0, stream>>>(yb, Wob, out, 4096, 2048, 2048, 1.0f, 1.0f, 2048, nullptr, 0, flag);
}

// Round 5
// 439.639 us; speedup vs baseline: 1.4816x; 1.0482x over previous
//
#include <hip/hip_runtime.h>
#include <hip/hip_bf16.h>

using bf16x8 = __attribute__((ext_vector_type(8))) __bf16;
using fx4    = __attribute__((ext_vector_type(4))) float;
using us4    = __attribute__((ext_vector_type(4))) unsigned short;
using us8    = __attribute__((ext_vector_type(8))) unsigned short;

__device__ __forceinline__ float b2f(unsigned short u) {
    unsigned int x = ((unsigned int)u) << 16;
    return __builtin_bit_cast(float, x);
}
__device__ __forceinline__ unsigned short f2b(float f) {
    __hip_bfloat16 h = __float2bfloat16(f);
    return __builtin_bit_cast(unsigned short, h);
}
__device__ __forceinline__ float logsigmoidf(float z) {
    return fminf(z, 0.0f) - log1pf(expf(-fabsf(z)));
}

// async 16B/lane global->LDS (dest = wave-uniform base + lane*16)
__device__ __forceinline__ void gl_lds16(const unsigned short* g, unsigned short* l) {
    __builtin_amdgcn_global_load_lds(
        (const __attribute__((address_space(1))) void*)g,
        (__attribute__((address_space(3))) void*)l, 16, 0, 0);
}

// 64-col bf16 LDS tile, 8-elem chunks XOR-swizzled by row&7 (2-way alias = free)
__device__ __forceinline__ bf16x8 frag64(const unsigned short* base, int row, int cq) {
    return *reinterpret_cast<const bf16x8*>(base + row * 64 + (((cq ^ (row & 7)) << 3)));
}
__device__ __forceinline__ int sw_idx(int row, int col) {
    return row * 64 + ((((col >> 3) ^ (row & 7)) << 3)) + (col & 7);
}

// ---------------------------------------------------------------------------
// dtype detect (flag=1 -> fp32 inputs)
// ---------------------------------------------------------------------------
__global__ __launch_bounds__(256) void detect_kernel(
    const unsigned int* __restrict__ x, int* __restrict__ flag)
{
    __shared__ int bad[256];
    const int t = threadIdx.x;
    int b = 0;
#pragma unroll
    for (int i = 0; i < 16; ++i) {
        unsigned int w = x[t * 16 + i];
        float v = b2f((unsigned short)(w & 0xFFFFu));
        if (!(fabsf(v) < 1.0e6f)) b = 1;
    }
    bad[t] = b;
    __syncthreads();
    for (int s = 128; s > 0; s >>= 1) {
        if (t < s) bad[t] |= bad[t + s];
        __syncthreads();
    }
    if (t == 0) flag[0] = bad[0];
}

// ---------------------------------------------------------------------------
// fused convert: all 10 inputs -> bf16 in one launch.
// ---------------------------------------------------------------------------
struct CvtArgs {
    const void* src[10];
    unsigned short* dst[10];
};

__global__ __launch_bounds__(256) void convert_all_kernel(
    CvtArgs a, const int* __restrict__ flag)
{
    const int pref[11] = {0, 8192, 10240, 12288, 12320, 12336, 12337,
                          16433, 20529, 20531, 24627};
    const int blk = blockIdx.x;
    int s = 0;
#pragma unroll
    for (int i = 1; i < 10; ++i) s += (blk >= pref[i]) ? 1 : 0;
    const int i0 = (blk - pref[s]) * 1024 + threadIdx.x * 4;
    if (*flag) {
        const float* sp = (const float*)a.src[s];
        fx4 v = *reinterpret_cast<const fx4*>(sp + i0);
        us4 r;
#pragma unroll
        for (int e = 0; e < 4; ++e) r[e] = f2b(v[e]);
        *reinterpret_cast<us4*>(a.dst[s] + i0) = r;
    } else {
        const unsigned short* sp = (const unsigned short*)a.src[s];
        *reinterpret_cast<us4*>(a.dst[s] + i0) =
            *reinterpret_cast<const us4*>(sp + i0);
    }
}

// ---------------------------------------------------------------------------
// GEMM (m97 structure): BK=64, XOR-swizzled unpadded LDS, global_load_lds.
// C = act(alpha(col) * (A@W^T) + bias); alpha = (col<asplit)?alpha_lo:alpha_hi
// ---------------------------------------------------------------------------
__global__ __launch_bounds__(256) void gemm_bt_kernel(
    const unsigned short* __restrict__ A, const unsigned short* __restrict__ W,
    unsigned short* __restrict__ C, int M, int N, int K,
    float alpha_lo, float alpha_hi, int asplit,
    const unsigned short* __restrict__ bias, int act,
    const int* __restrict__ oflag)
{
    __shared__ __align__(16) unsigned short As[128 * 64];
    __shared__ __align__(16) unsigned short Bs[128 * 64];

    const int tid  = threadIdx.x;
    const int lane = tid & 63, wid = tid >> 6;
    const int quad = lane >> 4, l15 = lane & 15;
    const int wm = (wid & 1) * 64, wn = (wid >> 1) * 64;
    const int m0 = blockIdx.y * 128, n0 = blockIdx.x * 128;

    fx4 acc[4][4];
#pragma unroll
    for (int i = 0; i < 4; ++i)
#pragma unroll
        for (int j = 0; j < 4; ++j) acc[i][j] = fx4{0.f, 0.f, 0.f, 0.f};

    const int srow = lane >> 3;
    const int g8   = ((lane & 7) ^ srow) * 8;
    const int c8   = (lane & 7) * 8;
    const unsigned short* Ab = A + (size_t)m0 * K;
    const unsigned short* Wb = W + (size_t)n0 * K;

    for (int k0 = 0; k0 < K; k0 += 64) {
#pragma unroll
        for (int p = 0; p < 4; ++p) {
            const int la  = wid * 4 + p;
            const int row = la * 8 + srow;
            gl_lds16(Ab + (size_t)row * K + k0 + g8, As + row * 64 + c8);
            gl_lds16(Wb + (size_t)row * K + k0 + g8, Bs + row * 64 + c8);
        }
        __syncthreads();
#pragma unroll
        for (int ks = 0; ks < 2; ++ks) {
            const int cq = quad + ks * 4;
            bf16x8 af[4], bfr[4];
#pragma unroll
            for (int mt = 0; mt < 4; ++mt) af[mt] = frag64(As, wm + mt * 16 + l15, cq);
#pragma unroll
            for (int nt = 0; nt < 4; ++nt) bfr[nt] = frag64(Bs, wn + nt * 16 + l15, cq);
#pragma unroll
            for (int mt = 0; mt < 4; ++mt)
#pragma unroll
                for (int nt = 0; nt < 4; ++nt)
                    acc[mt][nt] = __builtin_amdgcn_mfma_f32_16x16x32_bf16(
                        af[mt], bfr[nt], acc[mt][nt], 0, 0, 0);
        }
        __syncthreads();
    }

    const int f32out = oflag ? *oflag : 0;
#pragma unroll
    for (int nt = 0; nt < 4; ++nt) {
        const int ncol = n0 + wn + nt * 16 + l15;
        const float av = (ncol < asplit) ? alpha_lo : alpha_hi;
        const float bv = bias ? b2f(bias[ncol]) : 0.0f;
#pragma unroll
        for (int mt = 0; mt < 4; ++mt) {
#pragma unroll
            for (int r = 0; r < 4; ++r) {
                const int mrow = m0 + wm + mt * 16 + quad * 4 + r;
                float val = acc[mt][nt][r] * av + bv;
                if (act) val = val / (1.0f + __expf(-val));
                const size_t idx = (size_t)mrow * N + ncol;
                if (f32out) ((float*)C)[idx] = val;
                else        C[idx] = f2b(val);
            }
        }
    }
}

// ---------------------------------------------------------------------------
// gate1 v2: register-resident dot + wave shfl reduce (no LDS in hot path).
// block = one row m.  Ag <- logsigmoid(kg)/16  (not yet cumsummed)
// ---------------------------------------------------------------------------
__global__ __launch_bounds__(256) void gate1_kernel(
    const unsigned short* __restrict__ x, const unsigned short* __restrict__ Wkg1,
    const unsigned short* __restrict__ Wkg2, const unsigned short* __restrict__ bkg2,
    float* __restrict__ Ag)
{
    __shared__ float part[4][16];
    __shared__ float kgrow[16];
    const int m = blockIdx.x;
    const int tid = threadIdx.x;
    const int lane = tid & 63, w = tid >> 6;

    // x chunk in registers (one coalesced 16B load)
    us8 xv = *reinterpret_cast<const us8*>(x + (size_t)m * 2048 + tid * 8);
    float xr[8];
#pragma unroll
    for (int e = 0; e < 8; ++e) xr[e] = b2f(xv[e]);

    // 16 dot-partials, each: coalesced us8 Wkg1 load + 8 FMA + wave reduce
#pragma unroll
    for (int n = 0; n < 16; ++n) {
        us8 wv = *reinterpret_cast<const us8*>(Wkg1 + (size_t)n * 2048 + tid * 8);
        float s = 0.f;
#pragma unroll
        for (int e = 0; e < 8; ++e) s += xr[e] * b2f(wv[e]);
#pragma unroll
        for (int off = 1; off < 64; off <<= 1) s += __shfl_xor(s, off, 64);
        if (lane == 0) part[w][n] = s;
    }
    __syncthreads();
    if (tid < 16)
        kgrow[tid] = part[0][tid] + part[1][tid] + part[2][tid] + part[3][tid];
    __syncthreads();
    float kr[16];
#pragma unroll
    for (int j = 0; j < 16; ++j) kr[j] = kgrow[j];

    // low-rank projection + logsigmoid (4 gate cols per thread)
    const int b = m >> 11, l = m & 2047;
    const int c0 = tid * 4;
    const int h = c0 >> 6, d0 = c0 & 63;
    fx4 gv;
#pragma unroll
    for (int qi = 0; qi < 4; ++qi) {
        const int c = c0 + qi;
        us8 w0 = *reinterpret_cast<const us8*>(Wkg2 + (size_t)c * 16);
        us8 w1 = *reinterpret_cast<const us8*>(Wkg2 + (size_t)c * 16 + 8);
        float z = b2f(bkg2[c]);
#pragma unroll
        for (int j = 0; j < 8; ++j) z += kr[j] * b2f(w0[j]) + kr[8 + j] * b2f(w1[j]);
        gv[qi] = logsigmoidf(z) * 0.0625f;
    }
    *reinterpret_cast<fx4*>(Ag + ((size_t)(b * 16 + h) * 2048 + l) * 64 + d0) = gv;
}

// ---------------------------------------------------------------------------
// gate2: in-chunk (64) inclusive cumsum along t, in place.
// ---------------------------------------------------------------------------
__global__ __launch_bounds__(256) void gate2_kernel(float* __restrict__ Ag)
{
    const int gidx = blockIdx.x * 256 + threadIdx.x;   // 65536
    const int d = gidx & 63, ch = (gidx >> 6) & 31, bh = gidx >> 11;
    float* p = Ag + ((size_t)bh * 2048 + ch * 64) * 64 + d;
    float acc = 0.f;
#pragma unroll 8
    for (int t = 0; t < 64; ++t) {
        acc += p[(size_t)t * 64];
        p[(size_t)t * 64] = acc;
    }
}

// ---------------------------------------------------------------------------
// pass1 (MFMA): T^T[j][d] = sum_s v[s,j] * k[s,d]*exp(A63[d]-A[s][d])
// ---------------------------------------------------------------------------
__global__ __launch_bounds__(256) void pass1_kernel(
    const unsigned short* __restrict__ k, int kstr,
    const unsigned short* __restrict__ v,
    const float* __restrict__ Ag, float* __restrict__ Tc)
{
    __shared__ __align__(16) unsigned short kT[64 * 64];   // [d][s]
    __shared__ __align__(16) unsigned short vT[128 * 64];  // [j][s]

    const int blk = blockIdx.x;
    const int ch = blk & 31, bh = blk >> 5;
    const int b = bh >> 4, h = bh & 15;
    const int tid = threadIdx.x;
    const int lane = tid & 63, w = tid >> 6;
    const int quad = lane >> 4, l15 = lane & 15;

    const float* Abase = Ag + ((size_t)bh * 2048 + ch * 64) * 64;
    const unsigned short* kbase = k + ((size_t)(b * 2048 + ch * 64)) * kstr + h * 64;
    const unsigned short* vbase = v + ((size_t)(b * 2048 + ch * 64)) * 2048 + h * 128;

    {
        const int s = tid >> 2, d0 = (tid & 3) * 16;
        float av[16], a63[16];
        *(fx4*)(av)      = *(const fx4*)(Abase + (size_t)s * 64 + d0);
        *(fx4*)(av + 4)  = *(const fx4*)(Abase + (size_t)s * 64 + d0 + 4);
        *(fx4*)(av + 8)  = *(const fx4*)(Abase + (size_t)s * 64 + d0 + 8);
        *(fx4*)(av + 12) = *(const fx4*)(Abase + (size_t)s * 64 + d0 + 12);
        *(fx4*)(a63)      = *(const fx4*)(Abase + (size_t)63 * 64 + d0);
        *(fx4*)(a63 + 4)  = *(const fx4*)(Abase + (size_t)63 * 64 + d0 + 4);
        *(fx4*)(a63 + 8)  = *(const fx4*)(Abase + (size_t)63 * 64 + d0 + 8);
        *(fx4*)(a63 + 12) = *(const fx4*)(Abase + (size_t)63 * 64 + d0 + 12);
        us8 k0v = *(const us8*)(kbase + (size_t)s * kstr + d0);
        us8 k1v = *(const us8*)(kbase + (size_t)s * kstr + d0 + 8);
#pragma unroll
        for (int e = 0; e < 8; ++e) {
            kT[sw_idx(d0 + e, s)]     = f2b(b2f(k0v[e]) * __expf(a63[e] - av[e]));
            kT[sw_idx(d0 + 8 + e, s)] = f2b(b2f(k1v[e]) * __expf(a63[8 + e] - av[8 + e]));
        }
    }
    {
        const int s = tid >> 2, j0 = (tid & 3) * 32;
#pragma unroll
        for (int g2 = 0; g2 < 4; ++g2) {
            us8 vv = *(const us8*)(vbase + (size_t)s * 2048 + j0 + g2 * 8);
#pragma unroll
            for (int e = 0; e < 8; ++e) vT[sw_idx(j0 + g2 * 8 + e, s)] = vv[e];
        }
    }
    __syncthreads();

    bf16x8 bk[4][2];
#pragma unroll
    for (int nt = 0; nt < 4; ++nt) {
        bk[nt][0] = frag64(kT, nt * 16 + l15, quad);
        bk[nt][1] = frag64(kT, nt * 16 + l15, quad + 4);
    }
    fx4 acc[2][4];
#pragma unroll
    for (int mi = 0; mi < 2; ++mi)
#pragma unroll
        for (int nt = 0; nt < 4; ++nt) acc[mi][nt] = fx4{0.f, 0.f, 0.f, 0.f};
#pragma unroll
    for (int mi = 0; mi < 2; ++mi) {
        const int mrow = (w * 2 + mi) * 16 + l15;
        bf16x8 av0 = frag64(vT, mrow, quad);
        bf16x8 av1 = frag64(vT, mrow, quad + 4);
#pragma unroll
        for (int nt = 0; nt < 4; ++nt) {
            acc[mi][nt] = __builtin_amdgcn_mfma_f32_16x16x32_bf16(av0, bk[nt][0], acc[mi][nt], 0, 0, 0);
            acc[mi][nt] = __builtin_amdgcn_mfma_f32_16x16x32_bf16(av1, bk[nt][1], acc[mi][nt], 0, 0, 0);
        }
    }
    float* tb = Tc + (size_t)blk * 8192;
#pragma unroll
    for (int mi = 0; mi < 2; ++mi)
#pragma unroll
        for (int nt = 0; nt < 4; ++nt)
#pragma unroll
            for (int r = 0; r < 4; ++r) {
                const int j = (w * 2 + mi) * 16 + quad * 4 + r;
                const int d = nt * 16 + l15;
                tb[(size_t)j * 64 + d] = acc[mi][nt][r];
            }
}

// ---------------------------------------------------------------------------
// combine: scan 32 chunks; TS holds T^T [j][d] on entry, S_start^T on exit.
// ---------------------------------------------------------------------------
__global__ __launch_bounds__(256) void combine_kernel(
    float* __restrict__ TS, const float* __restrict__ Ag)
{
    const int blk = blockIdx.x;       // bh*4 + js
    const int js = blk & 3, bh = blk >> 2;
    const int tid = threadIdx.x;
    const int j = js * 32 + (tid >> 3), d0 = (tid & 7) * 8;
    float S[8] = {0.f, 0.f, 0.f, 0.f, 0.f, 0.f, 0.f, 0.f};
    const float* Abase = Ag + (size_t)bh * 2048 * 64;
    for (int c = 0; c < 32; ++c) {
        float* p = TS + ((size_t)(bh * 32 + c)) * 8192 + (size_t)j * 64 + d0;
        fx4 t1 = *(const fx4*)p;
        fx4 t2 = *(const fx4*)(p + 4);
        fx4 s1, s2;
#pragma unroll
        for (int e = 0; e < 4; ++e) { s1[e] = S[e]; s2[e] = S[4 + e]; }
        *(fx4*)p = s1;
        *(fx4*)(p + 4) = s2;
        const float* ab = Abase + ((size_t)c * 64 + 63) * 64 + d0;
        fx4 a1 = *(const fx4*)ab;
        fx4 a2 = *(const fx4*)(ab + 4);
#pragma unroll
        for (int e = 0; e < 4; ++e) {
            S[e]     = S[e]     * __expf(a1[e]) + t1[e];
            S[4 + e] = S[4 + e] * __expf(a2[e]) + t2[e];
        }
    }
}

// ---------------------------------------------------------------------------
// pass2 (MFMA): P = tri(Q~K~^T); O = Q~@S^T(hi/lo) + P@V; LN; silu-gate; y.
// ---------------------------------------------------------------------------
__global__ __launch_bounds__(256) void pass2_kernel(
    const unsigned short* __restrict__ q, const unsigned short* __restrict__ k,
    int qkstr,
    const unsigned short* __restrict__ v, const float* __restrict__ Ag,
    const float* __restrict__ Sst, const unsigned short* __restrict__ sg,
    unsigned short* __restrict__ y)
{
    __shared__ __align__(16) unsigned short qs[64 * 64];    // q~ [t][d]
    __shared__ __align__(16) unsigned short ksh[64 * 64];   // k~ [s][d]
    __shared__ __align__(16) unsigned short vT[128 * 64];   // v^T [j][s]
    __shared__ __align__(16) unsigned short Pb[64 * 64];    // P [t][s] bf16
    __shared__ __align__(16) unsigned short Ob[64 * 144];   // normalized O [t][j]

    const int blk = blockIdx.x;
    const int ch = blk & 31, bh = blk >> 5;
    const int b = bh >> 4, h = bh & 15;
    const int tid = threadIdx.x;
    const int lane = tid & 63, w = tid >> 6;
    const int quad = lane >> 4, l15 = lane & 15;

    const float* Abase = Ag + ((size_t)bh * 2048 + ch * 64) * 64;
    const unsigned short* qbase = q + ((size_t)(b * 2048 + ch * 64)) * qkstr + h * 64;
    const unsigned short* kbase = k + ((size_t)(b * 2048 + ch * 64)) * qkstr + h * 64;
    const unsigned short* vbase = v + ((size_t)(b * 2048 + ch * 64)) * 2048 + h * 128;

    {
        const int t = tid >> 2, d0 = (tid & 3) * 16;
        float av[16];
        *(fx4*)(av)      = *(const fx4*)(Abase + (size_t)t * 64 + d0);
        *(fx4*)(av + 4)  = *(const fx4*)(Abase + (size_t)t * 64 + d0 + 4);
        *(fx4*)(av + 8)  = *(const fx4*)(Abase + (size_t)t * 64 + d0 + 8);
        *(fx4*)(av + 12) = *(const fx4*)(Abase + (size_t)t * 64 + d0 + 12);
        us8 q0 = *(const us8*)(qbase + (size_t)t * qkstr + d0);
        us8 q1 = *(const us8*)(qbase + (size_t)t * qkstr + d0 + 8);
        us8 k0 = *(const us8*)(kbase + (size_t)t * qkstr + d0);
        us8 k1 = *(const us8*)(kbase + (size_t)t * qkstr + d0 + 8);
        us8 qo0, qo1, ko0, ko1;
#pragma unroll
        for (int e = 0; e < 8; ++e) {
            float e0 = __expf(av[e]),     n0 = __expf(-av[e]);
            float e1 = __expf(av[8 + e]), n1 = __expf(-av[8 + e]);
            qo0[e] = f2b(b2f(q0[e]) * e0);
            qo1[e] = f2b(b2f(q1[e]) * e1);
            ko0[e] = f2b(b2f(k0[e]) * n0);
            ko1[e] = f2b(b2f(k1[e]) * n1);
        }
        const int c0 = d0 >> 3, t7 = t & 7;
        *(us8*)(qs  + t * 64 + ((c0 ^ t7) << 3))       = qo0;
        *(us8*)(qs  + t * 64 + (((c0 + 1) ^ t7) << 3)) = qo1;
        *(us8*)(ksh + t * 64 + ((c0 ^ t7) << 3))       = ko0;
        *(us8*)(ksh + t * 64 + (((c0 + 1) ^ t7) << 3)) = ko1;
    }
    {
        const int s = tid >> 2, j0 = (tid & 3) * 32;
#pragma unroll
        for (int g2 = 0; g2 < 4; ++g2) {
            us8 vv = *(const us8*)(vbase + (size_t)s * 2048 + j0 + g2 * 8);
#pragma unroll
            for (int e = 0; e < 8; ++e) vT[sw_idx(j0 + g2 * 8 + e, s)] = vv[e];
        }
    }
    __syncthreads();

    bf16x8 aQ0 = frag64(qs, w * 16 + l15, quad);
    bf16x8 aQ1 = frag64(qs, w * 16 + l15, quad + 4);
    fx4 accP[4];
#pragma unroll
    for (int nt = 0; nt < 4; ++nt) accP[nt] = fx4{0.f, 0.f, 0.f, 0.f};
#pragma unroll
    for (int nt = 0; nt < 4; ++nt) {
        bf16x8 bK0 = frag64(ksh, nt * 16 + l15, quad);
        bf16x8 bK1 = frag64(ksh, nt * 16 + l15, quad + 4);
        accP[nt] = __builtin_amdgcn_mfma_f32_16x16x32_bf16(aQ0, bK0, accP[nt], 0, 0, 0);
        accP[nt] = __builtin_amdgcn_mfma_f32_16x16x32_bf16(aQ1, bK1, accP[nt], 0, 0, 0);
    }
#pragma unroll
    for (int nt = 0; nt < 4; ++nt)
#pragma unroll
        for (int r = 0; r < 4; ++r) {
            const int t = w * 16 + quad * 4 + r;
            const int s = nt * 16 + l15;
            Pb[sw_idx(t, s)] = f2b((s <= t) ? accP[nt][r] : 0.0f);
        }
    __syncthreads();

    bf16x8 aP0 = frag64(Pb, w * 16 + l15, quad);
    bf16x8 aP1 = frag64(Pb, w * 16 + l15, quad + 4);
    const float* ST = Sst + (size_t)blk * 8192;
    fx4 accO[8];
#pragma unroll
    for (int nt = 0; nt < 8; ++nt) accO[nt] = fx4{0.f, 0.f, 0.f, 0.f};
#pragma unroll
    for (int nt = 0; nt < 8; ++nt) {
        const int j = nt * 16 + l15;
        bf16x8 bV0 = frag64(vT, j, quad);
        bf16x8 bV1 = frag64(vT, j, quad + 4);
        const float* sp = ST + (size_t)j * 64 + quad * 8;
        fx4 s0a = *(const fx4*)(sp),      s0b = *(const fx4*)(sp + 4);
        fx4 s1a = *(const fx4*)(sp + 32), s1b = *(const fx4*)(sp + 36);
        us8 hi0u, lo0u, hi1u, lo1u;
#pragma unroll
        for (int e = 0; e < 4; ++e) {
            unsigned short hh;
            hh = f2b(s0a[e]); hi0u[e] = hh;     lo0u[e]     = f2b(s0a[e] - b2f(hh));
            hh = f2b(s0b[e]); hi0u[4 + e] = hh; lo0u[4 + e] = f2b(s0b[e] - b2f(hh));
            hh = f2b(s1a[e]); hi1u[e] = hh;     lo1u[e]     = f2b(s1a[e] - b2f(hh));
            hh = f2b(s1b[e]); hi1u[4 + e] = hh; lo1u[4 + e] = f2b(s1b[e] - b2f(hh));
        }
        bf16x8 hi0 = __builtin_bit_cast(bf16x8, hi0u);
        bf16x8 lo0 = __builtin_bit_cast(bf16x8, lo0u);
        bf16x8 hi1 = __builtin_bit_cast(bf16x8, hi1u);
        bf16x8 lo1 = __builtin_bit_cast(bf16x8, lo1u);
        accO[nt] = __builtin_amdgcn_mfma_f32_16x16x32_bf16(aP0, bV0, accO[nt], 0, 0, 0);
        accO[nt] = __builtin_amdgcn_mfma_f32_16x16x32_bf16(aP1, bV1, accO[nt], 0, 0, 0);
        accO[nt] = __builtin_amdgcn_mfma_f32_16x16x32_bf16(aQ0, hi0, accO[nt], 0, 0, 0);
        accO[nt] = __builtin_amdgcn_mfma_f32_16x16x32_bf16(aQ1, hi1, accO[nt], 0, 0, 0);
        accO[nt] = __builtin_amdgcn_mfma_f32_16x16x32_bf16(aQ0, lo0, accO[nt], 0, 0, 0);
        accO[nt] = __builtin_amdgcn_mfma_f32_16x16x32_bf16(aQ1, lo1, accO[nt], 0, 0, 0);
    }

    float sum1[4] = {0.f, 0.f, 0.f, 0.f}, sum2[4] = {0.f, 0.f, 0.f, 0.f};
#pragma unroll
    for (int nt = 0; nt < 8; ++nt)
#pragma unroll
        for (int r = 0; r < 4; ++r) {
            float ov = accO[nt][r];
            sum1[r] += ov;
            sum2[r] += ov * ov;
        }
#pragma unroll
    for (int m = 1; m < 16; m <<= 1)
#pragma unroll
        for (int r = 0; r < 4; ++r) {
            sum1[r] += __shfl_xor(sum1[r], m, 64);
            sum2[r] += __shfl_xor(sum2[r], m, 64);
        }
    float mu[4], inv[4];
#pragma unroll
    for (int r = 0; r < 4; ++r) {
        mu[r] = sum1[r] * (1.0f / 128.0f);
        float var = sum2[r] * (1.0f / 128.0f) - mu[r] * mu[r];
        inv[r] = rsqrtf(var + 1e-5f);
    }
#pragma unroll
    for (int nt = 0; nt < 8; ++nt)
#pragma unroll
        for (int r = 0; r < 4; ++r) {
            const int t = w * 16 + quad * 4 + r;
            Ob[t * 144 + nt * 16 + l15] = f2b((accO[nt][r] - mu[r]) * inv[r]);
        }
    __syncthreads();

    {
        const int t2 = tid >> 2, jg = (tid & 3) * 32;
        const size_t obase = ((size_t)(b * 2048 + ch * 64 + t2)) * 2048 + h * 128 + jg;
#pragma unroll
        for (int g2 = 0; g2 < 4; ++g2) {
            us8 ob = *(const us8*)(Ob + t2 * 144 + jg + g2 * 8);
            us8 gv = *(const us8*)(sg + obase + g2 * 8);
            us8 ov;
#pragma unroll
            for (int e = 0; e < 8; ++e) ov[e] = f2b(b2f(gv[e]) * b2f(ob[e]));
            *(us8*)(y + obase + g2 * 8) = ov;
        }
    }
}

// ---------------------------------------------------------------------------
extern "C" void kernel_launch(void* const* d_in, const int* in_sizes, int n_in,
                              void* d_out, int out_size, void* d_ws, size_t ws_size,
                              hipStream_t stream)
{
    unsigned short* out = (unsigned short*)d_out;

    char* ws = (char*)d_ws;
    size_t off = 0;
    auto alloc = [&](size_t bytes) -> void* {
        void* p = ws + off;
        off += (bytes + 255) & ~(size_t)255;
        return p;
    };
    unsigned short* xb    = (unsigned short*)alloc((size_t)4096 * 2048 * 2);
    unsigned short* Wqkb  = (unsigned short*)alloc((size_t)2048 * 2048 * 2); // [Wq;Wk]
    unsigned short* Wkg1b = (unsigned short*)alloc((size_t)16 * 2048 * 2);
    unsigned short* Wkg2b = (unsigned short*)alloc((size_t)1024 * 16 * 2);
    unsigned short* bkg2b = (unsigned short*)alloc((size_t)1024 * 2);
    unsigned short* Wvb   = (unsigned short*)alloc((size_t)2048 * 2048 * 2);
    unsigned short* Wgb   = (unsigned short*)alloc((size_t)2048 * 2048 * 2);
    unsigned short* bgb   = (unsigned short*)alloc((size_t)2048 * 2);
    unsigned short* Wob   = (unsigned short*)alloc((size_t)2048 * 2048 * 2);
    unsigned short* qkb  = (unsigned short*)alloc((size_t)4096 * 2048 * 2);  // q|k
    unsigned short* vb   = (unsigned short*)alloc((size_t)4096 * 2048 * 2);
    unsigned short* sgb  = (unsigned short*)alloc((size_t)4096 * 2048 * 2);
    unsigned short* yb   = (unsigned short*)alloc((size_t)4096 * 2048 * 2);
    float*          Agb  = (float*)alloc((size_t)4096 * 1024 * 4);
    float*          TS   = (float*)alloc((size_t)1024 * 8192 * 4);
    int*            flag = (int*)alloc(256);

    detect_kernel<<<1, 256, 0, stream>>>((const unsigned int*)d_in[0], flag);

    CvtArgs ca;
    ca.src[0] = d_in[0]; ca.dst[0] = xb;
    ca.src[1] = d_in[1]; ca.dst[1] = Wqkb;
    ca.src[2] = d_in[2]; ca.dst[2] = Wqkb + (size_t)1024 * 2048;
    ca.src[3] = d_in[3]; ca.dst[3] = Wkg1b;
    ca.src[4] = d_in[4]; ca.dst[4] = Wkg2b;
    ca.src[5] = d_in[5]; ca.dst[5] = bkg2b;
    ca.src[6] = d_in[6]; ca.dst[6] = Wvb;
    ca.src[7] = d_in[7]; ca.dst[7] = Wgb;
    ca.src[8] = d_in[8]; ca.dst[8] = bgb;
    ca.src[9] = d_in[9]; ca.dst[9] = Wob;
    convert_all_kernel<<<24627, 256, 0, stream>>>(ca, flag);

    const float SCALE = 0.08838834764831845f;  // 128**-0.5

    gemm_bt_kernel<<<dim3(16, 32), 256, 0, stream>>>(xb, Wqkb, qkb, 4096, 2048, 2048, 1.0f, SCALE, 1024, nullptr, 0, nullptr);
    gemm_bt_kernel<<<dim3(16, 32), 256, 0, stream>>>(xb, Wvb,  vb,  4096, 2048, 2048, 1.0f, 1.0f, 2048, nullptr, 0, nullptr);
    gemm_bt_kernel<<<dim3(16, 32), 256, 0, stream>>>(xb, Wgb,  sgb, 4096, 2048, 2048, 1.0f, 1.0f, 2048, bgb,     1, nullptr);
    gate1_kernel<<<4096, 256, 0, stream>>>(xb, Wkg1b, Wkg2b, bkg2b, Agb);
    gate2_kernel<<<256, 256, 0, stream>>>(Agb);
    pass1_kernel<<<1024, 256, 0, stream>>>(qkb + 1024, 2048, vb, Agb, TS);
    combine_kernel<<<128, 256, 0, stream>>>(TS, Agb);
    pass2_kernel<<<1024, 256, 0, stream>>>(qkb, qkb + 1024, 2048, vb, Agb, TS, sgb, yb);
    gemm_bt_kernel<<<dim3(16, 32), 256, 0, stream>>>(yb, Wob, out, 4096, 2048, 2048, 1.0f, 1.0f, 2048, nullptr, 0, flag);
}

// Round 6
// 419.739 us; speedup vs baseline: 1.5518x; 1.0474x over previous
//
#include <hip/hip_runtime.h>
#include <hip/hip_bf16.h>

using bf16x8 = __attribute__((ext_vector_type(8))) __bf16;
using fx4    = __attribute__((ext_vector_type(4))) float;
using us4    = __attribute__((ext_vector_type(4))) unsigned short;
using us8    = __attribute__((ext_vector_type(8))) unsigned short;

__device__ __forceinline__ float b2f(unsigned short u) {
    unsigned int x = ((unsigned int)u) << 16;
    return __builtin_bit_cast(float, x);
}
__device__ __forceinline__ unsigned short f2b(float f) {
    __hip_bfloat16 h = __float2bfloat16(f);
    return __builtin_bit_cast(unsigned short, h);
}
__device__ __forceinline__ float logsigmoidf(float z) {
    return fminf(z, 0.0f) - log1pf(expf(-fabsf(z)));
}

// async 16B/lane global->LDS (dest = wave-uniform base + lane*16)
__device__ __forceinline__ void gl_lds16(const unsigned short* g, unsigned short* l) {
    __builtin_amdgcn_global_load_lds(
        (const __attribute__((address_space(1))) void*)g,
        (__attribute__((address_space(3))) void*)l, 16, 0, 0);
}

// 64-col bf16 LDS tile, 8-elem chunks XOR-swizzled by row&7 (2-way alias = free)
__device__ __forceinline__ bf16x8 frag64(const unsigned short* base, int row, int cq) {
    return *reinterpret_cast<const bf16x8*>(base + row * 64 + (((cq ^ (row & 7)) << 3)));
}
__device__ __forceinline__ int sw_idx(int row, int col) {
    return row * 64 + ((((col >> 3) ^ (row & 7)) << 3)) + (col & 7);
}

// ---------------------------------------------------------------------------
// dtype detect (flag=1 -> fp32 inputs)
// ---------------------------------------------------------------------------
__global__ __launch_bounds__(256) void detect_kernel(
    const unsigned int* __restrict__ x, int* __restrict__ flag)
{
    __shared__ int bad[256];
    const int t = threadIdx.x;
    int b = 0;
#pragma unroll
    for (int i = 0; i < 16; ++i) {
        unsigned int w = x[t * 16 + i];
        float v = b2f((unsigned short)(w & 0xFFFFu));
        if (!(fabsf(v) < 1.0e6f)) b = 1;
    }
    bad[t] = b;
    __syncthreads();
    for (int s = 128; s > 0; s >>= 1) {
        if (t < s) bad[t] |= bad[t + s];
        __syncthreads();
    }
    if (t == 0) flag[0] = bad[0];
}

// ---------------------------------------------------------------------------
// fused convert: all 10 inputs -> bf16 in one launch.
// ---------------------------------------------------------------------------
struct CvtArgs {
    const void* src[10];
    unsigned short* dst[10];
};

__global__ __launch_bounds__(256) void convert_all_kernel(
    CvtArgs a, const int* __restrict__ flag)
{
    const int pref[11] = {0, 8192, 10240, 12288, 12320, 12336, 12337,
                          16433, 20529, 20531, 24627};
    const int blk = blockIdx.x;
    int s = 0;
#pragma unroll
    for (int i = 1; i < 10; ++i) s += (blk >= pref[i]) ? 1 : 0;
    const int i0 = (blk - pref[s]) * 1024 + threadIdx.x * 4;
    if (*flag) {
        const float* sp = (const float*)a.src[s];
        fx4 v = *reinterpret_cast<const fx4*>(sp + i0);
        us4 r;
#pragma unroll
        for (int e = 0; e < 4; ++e) r[e] = f2b(v[e]);
        *reinterpret_cast<us4*>(a.dst[s] + i0) = r;
    } else {
        const unsigned short* sp = (const unsigned short*)a.src[s];
        *reinterpret_cast<us4*>(a.dst[s] + i0) =
            *reinterpret_cast<const us4*>(sp + i0);
    }
}

// ---------------------------------------------------------------------------
// fused 3-output GEMM: x @ [Wq;Wk;Wv;Wg]^T  (N_total = 6144, 1536 blocks).
// Segment by global col: [0,2048)->qk (k-cols get SCALE), [2048,4096)->v,
// [4096,6144)->g (bias + silu). Out row stride 2048 per segment.
// ---------------------------------------------------------------------------
struct Seg3 {
    unsigned short* C0;   // qk
    unsigned short* C1;   // v
    unsigned short* C2;   // g (silu(x@Wg^T + bg))
    const unsigned short* bias2;
};

__global__ __launch_bounds__(256) void gemm_fused3_kernel(
    const unsigned short* __restrict__ A, const unsigned short* __restrict__ W,
    Seg3 segs, float scale_k)
{
    const int K = 2048;
    __shared__ __align__(16) unsigned short As[128 * 64];
    __shared__ __align__(16) unsigned short Bs[128 * 64];

    const int tid  = threadIdx.x;
    const int lane = tid & 63, wid = tid >> 6;
    const int quad = lane >> 4, l15 = lane & 15;
    const int wm = (wid & 1) * 64, wn = (wid >> 1) * 64;
    const int m0 = blockIdx.y * 128, n0 = blockIdx.x * 128;

    fx4 acc[4][4];
#pragma unroll
    for (int i = 0; i < 4; ++i)
#pragma unroll
        for (int j = 0; j < 4; ++j) acc[i][j] = fx4{0.f, 0.f, 0.f, 0.f};

    const int srow = lane >> 3;
    const int g8   = ((lane & 7) ^ srow) * 8;
    const int c8   = (lane & 7) * 8;
    const unsigned short* Ab = A + (size_t)m0 * K;
    const unsigned short* Wb = W + (size_t)n0 * K;

    for (int k0 = 0; k0 < K; k0 += 64) {
#pragma unroll
        for (int p = 0; p < 4; ++p) {
            const int la  = wid * 4 + p;
            const int row = la * 8 + srow;
            gl_lds16(Ab + (size_t)row * K + k0 + g8, As + row * 64 + c8);
            gl_lds16(Wb + (size_t)row * K + k0 + g8, Bs + row * 64 + c8);
        }
        __syncthreads();
#pragma unroll
        for (int ks = 0; ks < 2; ++ks) {
            const int cq = quad + ks * 4;
            bf16x8 af[4], bfr[4];
#pragma unroll
            for (int mt = 0; mt < 4; ++mt) af[mt] = frag64(As, wm + mt * 16 + l15, cq);
#pragma unroll
            for (int nt = 0; nt < 4; ++nt) bfr[nt] = frag64(Bs, wn + nt * 16 + l15, cq);
#pragma unroll
            for (int mt = 0; mt < 4; ++mt)
#pragma unroll
                for (int nt = 0; nt < 4; ++nt)
                    acc[mt][nt] = __builtin_amdgcn_mfma_f32_16x16x32_bf16(
                        af[mt], bfr[nt], acc[mt][nt], 0, 0, 0);
        }
        __syncthreads();
    }

    const int segi = n0 >> 11;  // block lies fully inside one 2048-col segment
    unsigned short* Cs = (segi == 0) ? segs.C0 : ((segi == 1) ? segs.C1 : segs.C2);
#pragma unroll
    for (int nt = 0; nt < 4; ++nt) {
        const int ncl = (n0 & 2047) + wn + nt * 16 + l15;   // col within segment
        const float av = (segi == 0 && ncl >= 1024) ? scale_k : 1.0f;
        const float bv = (segi == 2) ? b2f(segs.bias2[ncl]) : 0.0f;
#pragma unroll
        for (int mt = 0; mt < 4; ++mt) {
#pragma unroll
            for (int r = 0; r < 4; ++r) {
                const int mrow = m0 + wm + mt * 16 + quad * 4 + r;
                float val = acc[mt][nt][r] * av + bv;
                if (segi == 2) val = val / (1.0f + __expf(-val));
                Cs[(size_t)mrow * 2048 + ncl] = f2b(val);
            }
        }
    }
}

// ---------------------------------------------------------------------------
// GEMM (m97 structure) for the final y @ Wo^T; out bf16 or fp32 via *oflag.
// ---------------------------------------------------------------------------
__global__ __launch_bounds__(256) void gemm_bt_kernel(
    const unsigned short* __restrict__ A, const unsigned short* __restrict__ W,
    unsigned short* __restrict__ C, int M, int N, int K,
    const int* __restrict__ oflag)
{
    __shared__ __align__(16) unsigned short As[128 * 64];
    __shared__ __align__(16) unsigned short Bs[128 * 64];

    const int tid  = threadIdx.x;
    const int lane = tid & 63, wid = tid >> 6;
    const int quad = lane >> 4, l15 = lane & 15;
    const int wm = (wid & 1) * 64, wn = (wid >> 1) * 64;
    const int m0 = blockIdx.y * 128, n0 = blockIdx.x * 128;

    fx4 acc[4][4];
#pragma unroll
    for (int i = 0; i < 4; ++i)
#pragma unroll
        for (int j = 0; j < 4; ++j) acc[i][j] = fx4{0.f, 0.f, 0.f, 0.f};

    const int srow = lane >> 3;
    const int g8   = ((lane & 7) ^ srow) * 8;
    const int c8   = (lane & 7) * 8;
    const unsigned short* Ab = A + (size_t)m0 * K;
    const unsigned short* Wb = W + (size_t)n0 * K;

    for (int k0 = 0; k0 < K; k0 += 64) {
#pragma unroll
        for (int p = 0; p < 4; ++p) {
            const int la  = wid * 4 + p;
            const int row = la * 8 + srow;
            gl_lds16(Ab + (size_t)row * K + k0 + g8, As + row * 64 + c8);
            gl_lds16(Wb + (size_t)row * K + k0 + g8, Bs + row * 64 + c8);
        }
        __syncthreads();
#pragma unroll
        for (int ks = 0; ks < 2; ++ks) {
            const int cq = quad + ks * 4;
            bf16x8 af[4], bfr[4];
#pragma unroll
            for (int mt = 0; mt < 4; ++mt) af[mt] = frag64(As, wm + mt * 16 + l15, cq);
#pragma unroll
            for (int nt = 0; nt < 4; ++nt) bfr[nt] = frag64(Bs, wn + nt * 16 + l15, cq);
#pragma unroll
            for (int mt = 0; mt < 4; ++mt)
#pragma unroll
                for (int nt = 0; nt < 4; ++nt)
                    acc[mt][nt] = __builtin_amdgcn_mfma_f32_16x16x32_bf16(
                        af[mt], bfr[nt], acc[mt][nt], 0, 0, 0);
        }
        __syncthreads();
    }

    const int f32out = oflag ? *oflag : 0;
#pragma unroll
    for (int nt = 0; nt < 4; ++nt) {
        const int ncol = n0 + wn + nt * 16 + l15;
#pragma unroll
        for (int mt = 0; mt < 4; ++mt) {
#pragma unroll
            for (int r = 0; r < 4; ++r) {
                const int mrow = m0 + wm + mt * 16 + quad * 4 + r;
                float val = acc[mt][nt][r];
                const size_t idx = (size_t)mrow * N + ncol;
                if (f32out) ((float*)C)[idx] = val;
                else        C[idx] = f2b(val);
            }
        }
    }
}

// ---------------------------------------------------------------------------
// gate1: register-resident dot + wave shfl reduce.
// block = one row m.  Ag <- logsigmoid(kg)/16  (not yet cumsummed)
// ---------------------------------------------------------------------------
__global__ __launch_bounds__(256) void gate1_kernel(
    const unsigned short* __restrict__ x, const unsigned short* __restrict__ Wkg1,
    const unsigned short* __restrict__ Wkg2, const unsigned short* __restrict__ bkg2,
    float* __restrict__ Ag)
{
    __shared__ float part[4][16];
    __shared__ float kgrow[16];
    const int m = blockIdx.x;
    const int tid = threadIdx.x;
    const int lane = tid & 63, w = tid >> 6;

    us8 xv = *reinterpret_cast<const us8*>(x + (size_t)m * 2048 + tid * 8);
    float xr[8];
#pragma unroll
    for (int e = 0; e < 8; ++e) xr[e] = b2f(xv[e]);

#pragma unroll
    for (int n = 0; n < 16; ++n) {
        us8 wv = *reinterpret_cast<const us8*>(Wkg1 + (size_t)n * 2048 + tid * 8);
        float s = 0.f;
#pragma unroll
        for (int e = 0; e < 8; ++e) s += xr[e] * b2f(wv[e]);
#pragma unroll
        for (int off = 1; off < 64; off <<= 1) s += __shfl_xor(s, off, 64);
        if (lane == 0) part[w][n] = s;
    }
    __syncthreads();
    if (tid < 16)
        kgrow[tid] = part[0][tid] + part[1][tid] + part[2][tid] + part[3][tid];
    __syncthreads();
    float kr[16];
#pragma unroll
    for (int j = 0; j < 16; ++j) kr[j] = kgrow[j];

    const int b = m >> 11, l = m & 2047;
    const int c0 = tid * 4;
    const int h = c0 >> 6, d0 = c0 & 63;
    fx4 gv;
#pragma unroll
    for (int qi = 0; qi < 4; ++qi) {
        const int c = c0 + qi;
        us8 w0 = *reinterpret_cast<const us8*>(Wkg2 + (size_t)c * 16);
        us8 w1 = *reinterpret_cast<const us8*>(Wkg2 + (size_t)c * 16 + 8);
        float z = b2f(bkg2[c]);
#pragma unroll
        for (int j = 0; j < 8; ++j) z += kr[j] * b2f(w0[j]) + kr[8 + j] * b2f(w1[j]);
        gv[qi] = logsigmoidf(z) * 0.0625f;
    }
    *reinterpret_cast<fx4*>(Ag + ((size_t)(b * 16 + h) * 2048 + l) * 64 + d0) = gv;
}

// ---------------------------------------------------------------------------
// gate2: in-chunk (64) inclusive cumsum along t, in place.
// ---------------------------------------------------------------------------
__global__ __launch_bounds__(256) void gate2_kernel(float* __restrict__ Ag)
{
    const int gidx = blockIdx.x * 256 + threadIdx.x;   // 65536
    const int d = gidx & 63, ch = (gidx >> 6) & 31, bh = gidx >> 11;
    float* p = Ag + ((size_t)bh * 2048 + ch * 64) * 64 + d;
    float acc = 0.f;
#pragma unroll 8
    for (int t = 0; t < 64; ++t) {
        acc += p[(size_t)t * 64];
        p[(size_t)t * 64] = acc;
    }
}

// ---------------------------------------------------------------------------
// pass1 (MFMA): T^T[j][d] = sum_s v[s,j] * k[s,d]*exp(A63[d]-A[s][d])
// ---------------------------------------------------------------------------
__global__ __launch_bounds__(256) void pass1_kernel(
    const unsigned short* __restrict__ k, int kstr,
    const unsigned short* __restrict__ v,
    const float* __restrict__ Ag, float* __restrict__ Tc)
{
    __shared__ __align__(16) unsigned short kT[64 * 64];   // [d][s]
    __shared__ __align__(16) unsigned short vT[128 * 64];  // [j][s]

    const int blk = blockIdx.x;
    const int ch = blk & 31, bh = blk >> 5;
    const int b = bh >> 4, h = bh & 15;
    const int tid = threadIdx.x;
    const int lane = tid & 63, w = tid >> 6;
    const int quad = lane >> 4, l15 = lane & 15;

    const float* Abase = Ag + ((size_t)bh * 2048 + ch * 64) * 64;
    const unsigned short* kbase = k + ((size_t)(b * 2048 + ch * 64)) * kstr + h * 64;
    const unsigned short* vbase = v + ((size_t)(b * 2048 + ch * 64)) * 2048 + h * 128;

    {
        const int s = tid >> 2, d0 = (tid & 3) * 16;
        float av[16], a63[16];
        *(fx4*)(av)      = *(const fx4*)(Abase + (size_t)s * 64 + d0);
        *(fx4*)(av + 4)  = *(const fx4*)(Abase + (size_t)s * 64 + d0 + 4);
        *(fx4*)(av + 8)  = *(const fx4*)(Abase + (size_t)s * 64 + d0 + 8);
        *(fx4*)(av + 12) = *(const fx4*)(Abase + (size_t)s * 64 + d0 + 12);
        *(fx4*)(a63)      = *(const fx4*)(Abase + (size_t)63 * 64 + d0);
        *(fx4*)(a63 + 4)  = *(const fx4*)(Abase + (size_t)63 * 64 + d0 + 4);
        *(fx4*)(a63 + 8)  = *(const fx4*)(Abase + (size_t)63 * 64 + d0 + 8);
        *(fx4*)(a63 + 12) = *(const fx4*)(Abase + (size_t)63 * 64 + d0 + 12);
        us8 k0v = *(const us8*)(kbase + (size_t)s * kstr + d0);
        us8 k1v = *(const us8*)(kbase + (size_t)s * kstr + d0 + 8);
#pragma unroll
        for (int e = 0; e < 8; ++e) {
            kT[sw_idx(d0 + e, s)]     = f2b(b2f(k0v[e]) * __expf(a63[e] - av[e]));
            kT[sw_idx(d0 + 8 + e, s)] = f2b(b2f(k1v[e]) * __expf(a63[8 + e] - av[8 + e]));
        }
    }
    {
        const int s = tid >> 2, j0 = (tid & 3) * 32;
#pragma unroll
        for (int g2 = 0; g2 < 4; ++g2) {
            us8 vv = *(const us8*)(vbase + (size_t)s * 2048 + j0 + g2 * 8);
#pragma unroll
            for (int e = 0; e < 8; ++e) vT[sw_idx(j0 + g2 * 8 + e, s)] = vv[e];
        }
    }
    __syncthreads();

    bf16x8 bk[4][2];
#pragma unroll
    for (int nt = 0; nt < 4; ++nt) {
        bk[nt][0] = frag64(kT, nt * 16 + l15, quad);
        bk[nt][1] = frag64(kT, nt * 16 + l15, quad + 4);
    }
    fx4 acc[2][4];
#pragma unroll
    for (int mi = 0; mi < 2; ++mi)
#pragma unroll
        for (int nt = 0; nt < 4; ++nt) acc[mi][nt] = fx4{0.f, 0.f, 0.f, 0.f};
#pragma unroll
    for (int mi = 0; mi < 2; ++mi) {
        const int mrow = (w * 2 + mi) * 16 + l15;
        bf16x8 av0 = frag64(vT, mrow, quad);
        bf16x8 av1 = frag64(vT, mrow, quad + 4);
#pragma unroll
        for (int nt = 0; nt < 4; ++nt) {
            acc[mi][nt] = __builtin_amdgcn_mfma_f32_16x16x32_bf16(av0, bk[nt][0], acc[mi][nt], 0, 0, 0);
            acc[mi][nt] = __builtin_amdgcn_mfma_f32_16x16x32_bf16(av1, bk[nt][1], acc[mi][nt], 0, 0, 0);
        }
    }
    float* tb = Tc + (size_t)blk * 8192;
#pragma unroll
    for (int mi = 0; mi < 2; ++mi)
#pragma unroll
        for (int nt = 0; nt < 4; ++nt)
#pragma unroll
            for (int r = 0; r < 4; ++r) {
                const int j = (w * 2 + mi) * 16 + quad * 4 + r;
                const int d = nt * 16 + l15;
                tb[(size_t)j * 64 + d] = acc[mi][nt][r];
            }
}

// ---------------------------------------------------------------------------
// combine v2: 256 blocks, one fx4 chain per thread over the 32 chunks.
// TS holds T^T [j][d] on entry, S_start^T on exit.
// ---------------------------------------------------------------------------
__global__ __launch_bounds__(256) void combine_kernel(
    float* __restrict__ TS, const float* __restrict__ Ag)
{
    const int blk = blockIdx.x;       // bh*8 + js
    const int js = blk & 7, bh = blk >> 3;
    const int tid = threadIdx.x;
    const int j = js * 16 + (tid >> 4), d0 = (tid & 15) * 4;
    fx4 S = fx4{0.f, 0.f, 0.f, 0.f};
    const float* Abase = Ag + (size_t)bh * 2048 * 64;
    for (int c = 0; c < 32; ++c) {
        float* p = TS + ((size_t)(bh * 32 + c)) * 8192 + (size_t)j * 64 + d0;
        fx4 t = *(const fx4*)p;
        *(fx4*)p = S;
        fx4 a = *(const fx4*)(Abase + ((size_t)c * 64 + 63) * 64 + d0);
#pragma unroll
        for (int e = 0; e < 4; ++e) S[e] = S[e] * __expf(a[e]) + t[e];
    }
}

// ---------------------------------------------------------------------------
// pass2 (MFMA): P = tri(Q~K~^T); O = Q~@S^T(hi/lo) + P@V; LN; silu-gate; y.
// ---------------------------------------------------------------------------
__global__ __launch_bounds__(256) void pass2_kernel(
    const unsigned short* __restrict__ q, const unsigned short* __restrict__ k,
    int qkstr,
    const unsigned short* __restrict__ v, const float* __restrict__ Ag,
    const float* __restrict__ Sst, const unsigned short* __restrict__ sg,
    unsigned short* __restrict__ y)
{
    __shared__ __align__(16) unsigned short qs[64 * 64];    // q~ [t][d]
    __shared__ __align__(16) unsigned short ksh[64 * 64];   // k~ [s][d]
    __shared__ __align__(16) unsigned short vT[128 * 64];   // v^T [j][s]
    __shared__ __align__(16) unsigned short Pb[64 * 64];    // P [t][s] bf16
    __shared__ __align__(16) unsigned short Ob[64 * 144];   // normalized O [t][j]

    const int blk = blockIdx.x;
    const int ch = blk & 31, bh = blk >> 5;
    const int b = bh >> 4, h = bh & 15;
    const int tid = threadIdx.x;
    const int lane = tid & 63, w = tid >> 6;
    const int quad = lane >> 4, l15 = lane & 15;

    const float* Abase = Ag + ((size_t)bh * 2048 + ch * 64) * 64;
    const unsigned short* qbase = q + ((size_t)(b * 2048 + ch * 64)) * qkstr + h * 64;
    const unsigned short* kbase = k + ((size_t)(b * 2048 + ch * 64)) * qkstr + h * 64;
    const unsigned short* vbase = v + ((size_t)(b * 2048 + ch * 64)) * 2048 + h * 128;

    {
        const int t = tid >> 2, d0 = (tid & 3) * 16;
        float av[16];
        *(fx4*)(av)      = *(const fx4*)(Abase + (size_t)t * 64 + d0);
        *(fx4*)(av + 4)  = *(const fx4*)(Abase + (size_t)t * 64 + d0 + 4);
        *(fx4*)(av + 8)  = *(const fx4*)(Abase + (size_t)t * 64 + d0 + 8);
        *(fx4*)(av + 12) = *(const fx4*)(Abase + (size_t)t * 64 + d0 + 12);
        us8 q0 = *(const us8*)(qbase + (size_t)t * qkstr + d0);
        us8 q1 = *(const us8*)(qbase + (size_t)t * qkstr + d0 + 8);
        us8 k0 = *(const us8*)(kbase + (size_t)t * qkstr + d0);
        us8 k1 = *(const us8*)(kbase + (size_t)t * qkstr + d0 + 8);
        us8 qo0, qo1, ko0, ko1;
#pragma unroll
        for (int e = 0; e < 8; ++e) {
            float e0 = __expf(av[e]),     n0 = __expf(-av[e]);
            float e1 = __expf(av[8 + e]), n1 = __expf(-av[8 + e]);
            qo0[e] = f2b(b2f(q0[e]) * e0);
            qo1[e] = f2b(b2f(q1[e]) * e1);
            ko0[e] = f2b(b2f(k0[e]) * n0);
            ko1[e] = f2b(b2f(k1[e]) * n1);
        }
        const int c0 = d0 >> 3, t7 = t & 7;
        *(us8*)(qs  + t * 64 + ((c0 ^ t7) << 3))       = qo0;
        *(us8*)(qs  + t * 64 + (((c0 + 1) ^ t7) << 3)) = qo1;
        *(us8*)(ksh + t * 64 + ((c0 ^ t7) << 3))       = ko0;
        *(us8*)(ksh + t * 64 + (((c0 + 1) ^ t7) << 3)) = ko1;
    }
    {
        const int s = tid >> 2, j0 = (tid & 3) * 32;
#pragma unroll
        for (int g2 = 0; g2 < 4; ++g2) {
            us8 vv = *(const us8*)(vbase + (size_t)s * 2048 + j0 + g2 * 8);
#pragma unroll
            for (int e = 0; e < 8; ++e) vT[sw_idx(j0 + g2 * 8 + e, s)] = vv[e];
        }
    }
    __syncthreads();

    bf16x8 aQ0 = frag64(qs, w * 16 + l15, quad);
    bf16x8 aQ1 = frag64(qs, w * 16 + l15, quad + 4);
    fx4 accP[4];
#pragma unroll
    for (int nt = 0; nt < 4; ++nt) accP[nt] = fx4{0.f, 0.f, 0.f, 0.f};
#pragma unroll
    for (int nt = 0; nt < 4; ++nt) {
        bf16x8 bK0 = frag64(ksh, nt * 16 + l15, quad);
        bf16x8 bK1 = frag64(ksh, nt * 16 + l15, quad + 4);
        accP[nt] = __builtin_amdgcn_mfma_f32_16x16x32_bf16(aQ0, bK0, accP[nt], 0, 0, 0);
        accP[nt] = __builtin_amdgcn_mfma_f32_16x16x32_bf16(aQ1, bK1, accP[nt], 0, 0, 0);
    }
#pragma unroll
    for (int nt = 0; nt < 4; ++nt)
#pragma unroll
        for (int r = 0; r < 4; ++r) {
            const int t = w * 16 + quad * 4 + r;
            const int s = nt * 16 + l15;
            Pb[sw_idx(t, s)] = f2b((s <= t) ? accP[nt][r] : 0.0f);
        }
    __syncthreads();

    bf16x8 aP0 = frag64(Pb, w * 16 + l15, quad);
    bf16x8 aP1 = frag64(Pb, w * 16 + l15, quad + 4);
    const float* ST = Sst + (size_t)blk * 8192;
    fx4 accO[8];
#pragma unroll
    for (int nt = 0; nt < 8; ++nt) accO[nt] = fx4{0.f, 0.f, 0.f, 0.f};
#pragma unroll
    for (int nt = 0; nt < 8; ++nt) {
        const int j = nt * 16 + l15;
        bf16x8 bV0 = frag64(vT, j, quad);
        bf16x8 bV1 = frag64(vT, j, quad + 4);
        const float* sp = ST + (size_t)j * 64 + quad * 8;
        fx4 s0a = *(const fx4*)(sp),      s0b = *(const fx4*)(sp + 4);
        fx4 s1a = *(const fx4*)(sp + 32), s1b = *(const fx4*)(sp + 36);
        us8 hi0u, lo0u, hi1u, lo1u;
#pragma unroll
        for (int e = 0; e < 4; ++e) {
            unsigned short hh;
            hh = f2b(s0a[e]); hi0u[e] = hh;     lo0u[e]     = f2b(s0a[e] - b2f(hh));
            hh = f2b(s0b[e]); hi0u[4 + e] = hh; lo0u[4 + e] = f2b(s0b[e] - b2f(hh));
            hh = f2b(s1a[e]); hi1u[e] = hh;     lo1u[e]     = f2b(s1a[e] - b2f(hh));
            hh = f2b(s1b[e]); hi1u[4 + e] = hh; lo1u[4 + e] = f2b(s1b[e] - b2f(hh));
        }
        bf16x8 hi0 = __builtin_bit_cast(bf16x8, hi0u);
        bf16x8 lo0 = __builtin_bit_cast(bf16x8, lo0u);
        bf16x8 hi1 = __builtin_bit_cast(bf16x8, hi1u);
        bf16x8 lo1 = __builtin_bit_cast(bf16x8, lo1u);
        accO[nt] = __builtin_amdgcn_mfma_f32_16x16x32_bf16(aP0, bV0, accO[nt], 0, 0, 0);
        accO[nt] = __builtin_amdgcn_mfma_f32_16x16x32_bf16(aP1, bV1, accO[nt], 0, 0, 0);
        accO[nt] = __builtin_amdgcn_mfma_f32_16x16x32_bf16(aQ0, hi0, accO[nt], 0, 0, 0);
        accO[nt] = __builtin_amdgcn_mfma_f32_16x16x32_bf16(aQ1, hi1, accO[nt], 0, 0, 0);
        accO[nt] = __builtin_amdgcn_mfma_f32_16x16x32_bf16(aQ0, lo0, accO[nt], 0, 0, 0);
        accO[nt] = __builtin_amdgcn_mfma_f32_16x16x32_bf16(aQ1, lo1, accO[nt], 0, 0, 0);
    }

    float sum1[4] = {0.f, 0.f, 0.f, 0.f}, sum2[4] = {0.f, 0.f, 0.f, 0.f};
#pragma unroll
    for (int nt = 0; nt < 8; ++nt)
#pragma unroll
        for (int r = 0; r < 4; ++r) {
            float ov = accO[nt][r];
            sum1[r] += ov;
            sum2[r] += ov * ov;
        }
#pragma unroll
    for (int m = 1; m < 16; m <<= 1)
#pragma unroll
        for (int r = 0; r < 4; ++r) {
            sum1[r] += __shfl_xor(sum1[r], m, 64);
            sum2[r] += __shfl_xor(sum2[r], m, 64);
        }
    float mu[4], inv[4];
#pragma unroll
    for (int r = 0; r < 4; ++r) {
        mu[r] = sum1[r] * (1.0f / 128.0f);
        float var = sum2[r] * (1.0f / 128.0f) - mu[r] * mu[r];
        inv[r] = rsqrtf(var + 1e-5f);
    }
#pragma unroll
    for (int nt = 0; nt < 8; ++nt)
#pragma unroll
        for (int r = 0; r < 4; ++r) {
            const int t = w * 16 + quad * 4 + r;
            Ob[t * 144 + nt * 16 + l15] = f2b((accO[nt][r] - mu[r]) * inv[r]);
        }
    __syncthreads();

    {
        const int t2 = tid >> 2, jg = (tid & 3) * 32;
        const size_t obase = ((size_t)(b * 2048 + ch * 64 + t2)) * 2048 + h * 128 + jg;
#pragma unroll
        for (int g2 = 0; g2 < 4; ++g2) {
            us8 ob = *(const us8*)(Ob + t2 * 144 + jg + g2 * 8);
            us8 gv = *(const us8*)(sg + obase + g2 * 8);
            us8 ov;
#pragma unroll
            for (int e = 0; e < 8; ++e) ov[e] = f2b(b2f(gv[e]) * b2f(ob[e]));
            *(us8*)(y + obase + g2 * 8) = ov;
        }
    }
}

// ---------------------------------------------------------------------------
extern "C" void kernel_launch(void* const* d_in, const int* in_sizes, int n_in,
                              void* d_out, int out_size, void* d_ws, size_t ws_size,
                              hipStream_t stream)
{
    unsigned short* out = (unsigned short*)d_out;

    char* ws = (char*)d_ws;
    size_t off = 0;
    auto alloc = [&](size_t bytes) -> void* {
        void* p = ws + off;
        off += (bytes + 255) & ~(size_t)255;
        return p;
    };
    unsigned short* xb    = (unsigned short*)alloc((size_t)4096 * 2048 * 2);
    unsigned short* Wbig  = (unsigned short*)alloc((size_t)6144 * 2048 * 2); // [Wq;Wk;Wv;Wg]
    unsigned short* Wkg1b = (unsigned short*)alloc((size_t)16 * 2048 * 2);
    unsigned short* Wkg2b = (unsigned short*)alloc((size_t)1024 * 16 * 2);
    unsigned short* bkg2b = (unsigned short*)alloc((size_t)1024 * 2);
    unsigned short* bgb   = (unsigned short*)alloc((size_t)2048 * 2);
    unsigned short* Wob   = (unsigned short*)alloc((size_t)2048 * 2048 * 2);
    unsigned short* qkb  = (unsigned short*)alloc((size_t)4096 * 2048 * 2);  // q|k
    unsigned short* vb   = (unsigned short*)alloc((size_t)4096 * 2048 * 2);
    unsigned short* sgb  = (unsigned short*)alloc((size_t)4096 * 2048 * 2);
    unsigned short* yb   = (unsigned short*)alloc((size_t)4096 * 2048 * 2);
    float*          Agb  = (float*)alloc((size_t)4096 * 1024 * 4);
    float*          TS   = (float*)alloc((size_t)1024 * 8192 * 4);
    int*            flag = (int*)alloc(256);

    detect_kernel<<<1, 256, 0, stream>>>((const unsigned int*)d_in[0], flag);

    CvtArgs ca;
    ca.src[0] = d_in[0]; ca.dst[0] = xb;
    ca.src[1] = d_in[1]; ca.dst[1] = Wbig;                         // Wq
    ca.src[2] = d_in[2]; ca.dst[2] = Wbig + (size_t)1024 * 2048;   // Wk
    ca.src[3] = d_in[3]; ca.dst[3] = Wkg1b;
    ca.src[4] = d_in[4]; ca.dst[4] = Wkg2b;
    ca.src[5] = d_in[5]; ca.dst[5] = bkg2b;
    ca.src[6] = d_in[6]; ca.dst[6] = Wbig + (size_t)2048 * 2048;   // Wv
    ca.src[7] = d_in[7]; ca.dst[7] = Wbig + (size_t)4096 * 2048;   // Wg
    ca.src[8] = d_in[8]; ca.dst[8] = bgb;
    ca.src[9] = d_in[9]; ca.dst[9] = Wob;
    convert_all_kernel<<<24627, 256, 0, stream>>>(ca, flag);

    const float SCALE = 0.08838834764831845f;  // 128**-0.5

    Seg3 segs;
    segs.C0 = qkb; segs.C1 = vb; segs.C2 = sgb; segs.bias2 = bgb;
    gemm_fused3_kernel<<<dim3(48, 32), 256, 0, stream>>>(xb, Wbig, segs, SCALE);

    gate1_kernel<<<4096, 256, 0, stream>>>(xb, Wkg1b, Wkg2b, bkg2b, Agb);
    gate2_kernel<<<256, 256, 0, stream>>>(Agb);
    pass1_kernel<<<1024, 256, 0, stream>>>(qkb + 1024, 2048, vb, Agb, TS);
    combine_kernel<<<256, 256, 0, stream>>>(TS, Agb);
    pass2_kernel<<<1024, 256, 0, stream>>>(qkb, qkb + 1024, 2048, vb, Agb, TS, sgb, yb);
    gemm_bt_kernel<<<dim3(16, 32), 256, 0, stream>>>(yb, Wob, out, 4096, 2048, 2048, flag);
}